// Round 25
// baseline (115.171 us; speedup 1.0000x reference)
//
#include <hip/hip_runtime.h>
#include <stdint.h>

typedef unsigned char u8;
typedef unsigned short u16;
typedef __attribute__((ext_vector_type(4))) float f32x4;
typedef __attribute__((ext_vector_type(2))) uint32_t u32x2;

#define B_      16
#define L_      1024
#define H_      1024
#define G_      128
#define M_TOT   16368            // B*(L-1)
#define K_TOT   3072
#define OUT_SEG 2095104          // M_TOT*G_
#define KL_IDX  (4*OUT_SEG)
#define KL_BLOCKS 2046           // M_TOT / 8 exactly
#define WSCALE  128.0f
#define WINV    0.0078125f       // 1/128

// ws layout
#define WS_WT_OFF    0           // fp8 W'T [512][3072] = 1,572,864 B
#define WS_BIAS_OFF  1572864     // float[512]
#define WS_PART_OFF  1574912     // float[2046] block partials

__device__ inline void gload16(const void* g, void* l) {
    __builtin_amdgcn_global_load_lds(
        (const __attribute__((address_space(1))) void*)g,
        (__attribute__((address_space(3))) void*)l, 16, 0, 0);
}

// pack 4 floats -> 4 fp8 (e4m3, OCP on gfx950) in one u32, k-ascending bytes
__device__ inline uint32_t pk4fp8(float f0, float f1, float f2, float f3) {
    uint32_t w = __builtin_amdgcn_cvt_pk_fp8_f32(f0, f1, 0, 0);
    w = __builtin_amdgcn_cvt_pk_fp8_f32(f2, f3, w, 1);
    return w;
}

// ---------------- prep: build W'T fp8 (x128) [512][3072] + bias[512] ---------
__global__ __launch_bounds__(256) void prep_kernel(
    const float* __restrict__ Wzm, const float* __restrict__ bzm,
    const float* __restrict__ Wzv, const float* __restrict__ bzv,
    const float* __restrict__ Wqm, const float* __restrict__ bqm,
    const float* __restrict__ Wqv, const float* __restrict__ bqv,
    u8* __restrict__ wt, float* __restrict__ bias)
{
    const int ng = blockIdx.x >> 2;
    const int kq = blockIdx.x & 3;
    const int n0 = ng * 8;
    const float* W; const float* bsrc; int g0; int kmax;
    if (n0 < 128)      { W = Wzm; bsrc = bzm; g0 = n0;       kmax = 2048; }
    else if (n0 < 256) { W = Wzv; bsrc = bzv; g0 = n0 - 128; kmax = 2048; }
    else if (n0 < 384) { W = Wqm; bsrc = bqm; g0 = n0 - 256; kmax = 3072; }
    else               { W = Wqv; bsrc = bqv; g0 = n0 - 384; kmax = 3072; }
    const int tid = threadIdx.x;
    if (kq == 0 && tid < 8) bias[n0 + tid] = bsrc[g0 + tid];

    __shared__ float lt[8][260];
    const int go = tid & 7;
    const int kk = tid >> 3;
    const int nn = tid >> 5;
    const int kc = (tid & 31) * 8;

    for (int i = 0; i < 3; ++i) {
        int kbase = kq * 768 + i * 256;
        __syncthreads();
        #pragma unroll
        for (int kk2 = 0; kk2 < 8; ++kk2) {
            int k = kbase + kk2 * 32 + kk;
            float v = (k < kmax) ? W[(size_t)k * G_ + g0 + go] : 0.0f;
            lt[go][kk2 * 32 + kk] = v;
        }
        __syncthreads();
        uint32_t u0 = pk4fp8(lt[nn][kc + 0] * WSCALE, lt[nn][kc + 1] * WSCALE,
                             lt[nn][kc + 2] * WSCALE, lt[nn][kc + 3] * WSCALE);
        uint32_t u1 = pk4fp8(lt[nn][kc + 4] * WSCALE, lt[nn][kc + 5] * WSCALE,
                             lt[nn][kc + 6] * WSCALE, lt[nn][kc + 7] * WSCALE);
        *(u32x2*)&wt[(size_t)(n0 + nn) * K_TOT + kbase + kc] = (u32x2){u0, u1};
    }
}

// ---------------- GEMM: out[m, 0:512] = ce @ W' + bias (fp8 MFMA) -----------
// fp8 champion schedule with BK=128 (24 K-tiles): BM=128, BN=128, 512 thr
// (8 waves, 2x4 of 64x32), grid 512 -> 2 blocks/CU.
// Tiles [128 rows][128 fp8] = 16KB; LDS = 2*(16+16) = 64KB.
//   A: global f32x4 (64B/row coalesced, j=0..7) -> P/Q named reg sets
//      (2-deep) -> cvt_pk_fp8 -> swizzled ds_write_b32 x8.
//   B: fp8 wt via global_load_lds x2, 16B-chunk source-preswizzled.
// Swizzle (row = 128B = 8 chunks of 16B): chunk ^= row&7; element k at byte
//   row*128 + (((k>>4) ^ (row&7))<<4) + (k&15).  (2-way = free everywhere)
// Counted vmcnt: 10 VMEM/thread/phase (8 A + 2 B); WAITV(10) drains
// exactly {B(t), Aregs(t+1)}; never 0 in the main loop.
__global__ __launch_bounds__(512, 2) void gemm_kernel(
    const float* __restrict__ events, const float* __restrict__ contexts,
    const u8* __restrict__ wt, const float* __restrict__ bias,
    float* __restrict__ out)
{
    __shared__ u8 Ab[2][128 * 128];   // fp8 A tiles, swizzled (16 KB each)
    __shared__ u8 Bs[2][128 * 128];   // fp8 B tiles, swizzled (16 KB each)

    const int tid = threadIdx.x;
    const int bid = blockIdx.x;
    // 4 nb-blocks of an A panel share bid&7 -> same XCD.
    const int xx  = bid & 7;
    const int jj  = bid >> 3;            // 0..63
    const int nb  = jj & 3;
    const int mp  = (jj >> 2) * 8 + xx;  // 0..127
    const int m0  = mp * 128;

    const int lane = tid & 63;
    const int w    = tid >> 6;           // 0..7
    const int wm   = (w >> 2) * 64;      // 0 or 64
    const int wn   = (w & 3) * 32;       // 0,32,64,96
    const int lr   = lane & 15;
    const int kg   = lane >> 4;          // k-octet 0..3 within 32-k MFMA step

    // ---- A staging: row r = tid>>2 (0..127), quarter q = tid&3 ----
    // instr j (0..7): 4 lanes of a row read contiguous 64B at k=j*16+q*4.
    const int r = tid >> 2;
    const int q = tid & 3;
    int m = m0 + r; if (m > M_TOT - 1) m = M_TOT - 1;
    int bb = m / 1023;
    int tt = m - bb * 1023;
    const float* paE = events   + ((size_t)(bb * L_ + tt)) * H_;
    const float* paC = contexts + ((size_t)(bb * (L_ - 1) + tt)) * H_;
    // swizzled ds_write_b32 byte offsets: chunk j ^ (r&7), within-chunk q*4
    int aw[8];
    #pragma unroll
    for (int j = 0; j < 8; ++j)
        aw[j] = r * 128 + ((j ^ (r & 7)) << 4) + q * 4;

    // ---- B staging: 2 gload16/thread, source-preswizzled (16B chunks) ----
    const u8* bS[2];
    #pragma unroll
    for (int it = 0; it < 2; ++it) {
        int c  = it * 512 + tid;         // 0..1023
        int v  = c >> 3;                 // row 0..127
        int cs = (c & 7) ^ (v & 7);      // source chunk
        bS[it] = wt + (size_t)(nb * 128 + v) * K_TOT + cs * 16;
    }

    // ---- fragment read offsets (bytes; element k = ks*32 + kg*8) ----
    int aoff[4][4], boff[2][4];
    #pragma unroll
    for (int i = 0; i < 4; ++i) {
        int row = wm + i * 16 + lr;
        #pragma unroll
        for (int ks = 0; ks < 4; ++ks) {
            int c16 = ks * 2 + (kg >> 1);
            aoff[i][ks] = row * 128 + ((c16 ^ (row & 7)) << 4) + (kg & 1) * 8;
        }
    }
    #pragma unroll
    for (int j = 0; j < 2; ++j) {
        int nn = wn + j * 16 + lr;
        #pragma unroll
        for (int ks = 0; ks < 4; ++ks) {
            int c16 = ks * 2 + (kg >> 1);
            boff[j][ks] = nn * 128 + ((c16 ^ (nn & 7)) << 4) + (kg & 1) * 8;
        }
    }

    f32x4 acc[4][2];
    #pragma unroll
    for (int i = 0; i < 4; ++i)
        #pragma unroll
        for (int j = 0; j < 2; ++j)
            acc[i][j] = (f32x4){0.f, 0.f, 0.f, 0.f};

    auto stageB = [&](int buf, int kt) {
        int k0 = kt * 128;
        gload16(bS[0] + k0, &Bs[buf][tid * 16]);
        gload16(bS[1] + k0, &Bs[buf][(512 + tid) * 16]);
    };
    auto compute = [&](int buf) {
        #pragma unroll
        for (int ks = 0; ks < 4; ++ks) {
            long a[4], bf[2];
            #pragma unroll
            for (int i = 0; i < 4; ++i)
                a[i] = *(const long*)&Ab[buf][aoff[i][ks]];
            #pragma unroll
            for (int j = 0; j < 2; ++j)
                bf[j] = *(const long*)&Bs[buf][boff[j][ks]];
            __builtin_amdgcn_s_setprio(1);
            #pragma unroll
            for (int i = 0; i < 4; ++i)
                #pragma unroll
                for (int j = 0; j < 2; ++j)
                    acc[i][j] = __builtin_amdgcn_mfma_f32_16x16x32_fp8_fp8(
                        a[i], bf[j], acc[i][j], 0, 0, 0);
            __builtin_amdgcn_s_setprio(0);
        }
    };

    // Named A-staging register sets (2-phase-deep; no arrays -> no scratch)
    f32x4 P0, P1, P2, P3, P4, P5, P6, P7;
    f32x4 Q0, Q1, Q2, Q3, Q4, Q5, Q6, Q7;

#define LOADA(p, KT)                                                           \
    {                                                                          \
        int rg_ = (KT) >> 3;                                                   \
        int kq_ = (((KT) & 7) << 7) + q * 4;                                   \
        const float* s_ = (rg_ == 0) ? paE : (rg_ == 1 ? (paE + H_) : paC);    \
        s_ += kq_;                                                             \
        p##0 = *(const f32x4*)(s_ +   0);                                      \
        p##1 = *(const f32x4*)(s_ +  16);                                      \
        p##2 = *(const f32x4*)(s_ +  32);                                      \
        p##3 = *(const f32x4*)(s_ +  48);                                      \
        p##4 = *(const f32x4*)(s_ +  64);                                      \
        p##5 = *(const f32x4*)(s_ +  80);                                      \
        p##6 = *(const f32x4*)(s_ +  96);                                      \
        p##7 = *(const f32x4*)(s_ + 112);                                      \
    }
#define CVT1(p, J, BUF)                                                        \
    {                                                                          \
        uint32_t w_ = pk4fp8(p##J[0], p##J[1], p##J[2], p##J[3]);              \
        *(uint32_t*)&Ab[BUF][aw[J]] = w_;                                      \
    }
#define CVTW(p, BUF)                                                           \
    CVT1(p, 0, BUF) CVT1(p, 1, BUF) CVT1(p, 2, BUF) CVT1(p, 3, BUF)            \
    CVT1(p, 4, BUF) CVT1(p, 5, BUF) CVT1(p, 6, BUF) CVT1(p, 7, BUF)

#define WAITV(N)                                                               \
    asm volatile("s_waitcnt vmcnt(" #N ")" ::: "memory");                      \
    __builtin_amdgcn_sched_barrier(0);
#define LGKM0                                                                  \
    asm volatile("s_waitcnt lgkmcnt(0)" ::: "memory");                         \
    __builtin_amdgcn_sched_barrier(0);
#define BAR __builtin_amdgcn_s_barrier()

    // prologue: A(0)->regs->Ab[0]; B(0) in flight; A(1)->Q (in flight)
    LOADA(P, 0);
    stageB(0, 0);
    WAITV(2);            // drain P = A(0) regs, leave B(0)
    CVTW(P, 0);
    LOADA(Q, 1);         // outstanding: B(0) 2 + Q 8 = 10
    LGKM0;               // prologue ds_writes done before first barrier

    for (int t = 0; t < 22; t += 2) {
        // phase t (buf0): consume Q=A(t+1) after WAITV
        LOADA(P, t + 2);
        stageB(1, t + 1);
        WAITV(10); BAR;                // drains B(t) + Q regs
        compute(0);
        CVTW(Q, 1);
        LGKM0; BAR;
        // phase t+1 (buf1)
        LOADA(Q, t + 3);
        stageB(0, t + 2);
        WAITV(10); BAR;                // drains B(t+1) + P regs
        compute(1);
        CVTW(P, 0);
        LGKM0; BAR;
    }
    // phase 22 (buf0): Q holds A(23); no more A loads
    stageB(1, 23);
    WAITV(2); BAR;                     // drains B(22) + Q regs, leaves B(23)
    compute(0);
    CVTW(Q, 1);
    LGKM0; BAR;
    // phase 23 (buf1)
    WAITV(0); BAR;
    compute(1);

#undef LOADA
#undef CVT1
#undef CVTW
#undef WAITV
#undef LGKM0
#undef BAR

    // epilogue: row = m0 + wm + i*16 + kg*4 + rr ; gcol = nb*128 + wn + j*16 + lr
    // un-scale W (x128) by WINV.
    const float* bptr = bias + nb * 128;
    float* obase = out + (size_t)nb * OUT_SEG;
    #pragma unroll
    for (int i = 0; i < 4; ++i) {
        int mloc = wm + i * 16 + kg * 4;
        #pragma unroll
        for (int j = 0; j < 2; ++j) {
            int g = wn + j * 16 + lr;
            float bv2 = bptr[g];
            #pragma unroll
            for (int rr = 0; rr < 4; ++rr) {
                int mo = m0 + mloc + rr;
                if (mo < M_TOT)
                    obase[(size_t)mo * G_ + g] = acc[i][j][rr] * WINV + bv2;
            }
        }
    }
}

// ---------------- KL reduction: stage 1 (f32x4 loads, 8 rows/block) ----------
__global__ __launch_bounds__(256) void kl_kernel(const float* __restrict__ out,
                                                 float* __restrict__ partial)
{
    int row  = blockIdx.x * 8 + (threadIdx.x >> 5);   // 2046*8 = M_TOT
    int col  = (threadIdx.x & 31) * 4;
    const float* zm  = out;
    const float* zlv = out + OUT_SEG;
    const float* qm  = out + (size_t)2 * OUT_SEG;
    const float* qlv = out + (size_t)3 * OUT_SEG;
    size_t base = (size_t)row * G_ + col;
    f32x4 a = *(const f32x4*)&zm[base];
    f32x4 b = *(const f32x4*)&zlv[base];
    f32x4 c = *(const f32x4*)&qm[base];
    f32x4 d = *(const f32x4*)&qlv[base];
    float s = 0.f;
    #pragma unroll
    for (int e = 0; e < 4; ++e) {
        float diff = a[e] - c[e];
        s += d[e] - b[e] + (__expf(b[e]) + diff * diff) * __expf(-d[e]) - 1.0f;
    }
    #pragma unroll
    for (int off = 32; off > 0; off >>= 1)
        s += __shfl_down(s, off);
    __shared__ float pw[4];
    int wid  = threadIdx.x >> 6;
    int lane = threadIdx.x & 63;
    if (lane == 0) pw[wid] = s;
    __syncthreads();
    if (threadIdx.x == 0)
        partial[blockIdx.x] = pw[0] + pw[1] + pw[2] + pw[3];
}

// ---------------- KL reduction: stage 2 --------------------------------------
__global__ __launch_bounds__(256) void kl_final(const float* __restrict__ partial,
                                                float* __restrict__ out)
{
    float s = 0.f;
    for (int i = threadIdx.x; i < KL_BLOCKS; i += 256) s += partial[i];
    #pragma unroll
    for (int off = 32; off > 0; off >>= 1)
        s += __shfl_down(s, off);
    __shared__ float pw[4];
    int wid = threadIdx.x >> 6;
    int lane = threadIdx.x & 63;
    if (lane == 0) pw[wid] = s;
    __syncthreads();
    if (threadIdx.x == 0)
        out[KL_IDX] = 0.5f * (pw[0] + pw[1] + pw[2] + pw[3]) / (float)M_TOT;
}

// ---------------- launcher ----------------------------------------------------
extern "C" void kernel_launch(void* const* d_in, const int* in_sizes, int n_in,
                              void* d_out, int out_size, void* d_ws, size_t ws_size,
                              hipStream_t stream)
{
    const float* events   = (const float*)d_in[0];
    const float* contexts = (const float*)d_in[1];
    const float* Wzm = (const float*)d_in[2];
    const float* bzm = (const float*)d_in[3];
    const float* Wzv = (const float*)d_in[4];
    const float* bzv = (const float*)d_in[5];
    const float* Wqm = (const float*)d_in[6];
    const float* bqm = (const float*)d_in[7];
    const float* Wqv = (const float*)d_in[8];
    const float* bqv = (const float*)d_in[9];
    float* out = (float*)d_out;

    u8*    wt      = (u8*)((char*)d_ws + WS_WT_OFF);
    float* bias    = (float*)((char*)d_ws + WS_BIAS_OFF);
    float* partial = (float*)((char*)d_ws + WS_PART_OFF);

    prep_kernel<<<256, 256, 0, stream>>>(Wzm, bzm, Wzv, bzv, Wqm, bqm, Wqv, bqv,
                                         wt, bias);
    gemm_kernel<<<512, 512, 0, stream>>>(events, contexts, wt, bias, out);
    kl_kernel<<<KL_BLOCKS, 256, 0, stream>>>(out, partial);
    kl_final<<<1, 256, 0, stream>>>(partial, out);
}

// Round 26
// 90.505 us; speedup vs baseline: 1.2725x; 1.2725x over previous
//
#include <hip/hip_runtime.h>
#include <stdint.h>

typedef unsigned char u8;
typedef unsigned short u16;
typedef __attribute__((ext_vector_type(8))) short short8;
typedef __attribute__((ext_vector_type(4))) float f32x4;
typedef __attribute__((ext_vector_type(2))) uint32_t u32x2;

#define B_      16
#define L_      1024
#define H_      1024
#define G_      128
#define M_TOT   16368            // B*(L-1)
#define K_TOT   3072
#define OUT_SEG 2095104          // M_TOT*G_
#define KL_IDX  (4*OUT_SEG)
#define KL_BLOCKS 2046           // M_TOT / 8 exactly
#define WSCALE  128.0f
#define WINV    0.0078125f       // 1/128

// ws layout
#define WS_WT_OFF    0           // fp8 W'T [512][3072] = 1,572,864 B
#define WS_BIAS_OFF  1572864     // float[512]
#define WS_PART_OFF  1574912     // float[2046] block partials

__device__ inline void gload16(const void* g, void* l) {
    __builtin_amdgcn_global_load_lds(
        (const __attribute__((address_space(1))) void*)g,
        (__attribute__((address_space(3))) void*)l, 16, 0, 0);
}

// pack 4 floats -> 4 fp8 (e4m3, OCP on gfx950) in one u32, k-ascending bytes
__device__ inline uint32_t pk4fp8(float f0, float f1, float f2, float f3) {
    uint32_t w = __builtin_amdgcn_cvt_pk_fp8_f32(f0, f1, 0, 0);
    w = __builtin_amdgcn_cvt_pk_fp8_f32(f2, f3, w, 1);
    return w;
}

// ---------------- prep: build W'T fp8 (x128) [512][3072] + bias[512] ---------
__global__ __launch_bounds__(256) void prep_kernel(
    const float* __restrict__ Wzm, const float* __restrict__ bzm,
    const float* __restrict__ Wzv, const float* __restrict__ bzv,
    const float* __restrict__ Wqm, const float* __restrict__ bqm,
    const float* __restrict__ Wqv, const float* __restrict__ bqv,
    u8* __restrict__ wt, float* __restrict__ bias)
{
    const int ng = blockIdx.x >> 2;
    const int kq = blockIdx.x & 3;
    const int n0 = ng * 8;
    const float* W; const float* bsrc; int g0; int kmax;
    if (n0 < 128)      { W = Wzm; bsrc = bzm; g0 = n0;       kmax = 2048; }
    else if (n0 < 256) { W = Wzv; bsrc = bzv; g0 = n0 - 128; kmax = 2048; }
    else if (n0 < 384) { W = Wqm; bsrc = bqm; g0 = n0 - 256; kmax = 3072; }
    else               { W = Wqv; bsrc = bqv; g0 = n0 - 384; kmax = 3072; }
    const int tid = threadIdx.x;
    if (kq == 0 && tid < 8) bias[n0 + tid] = bsrc[g0 + tid];

    __shared__ float lt[8][260];
    const int go = tid & 7;
    const int kk = tid >> 3;
    const int nn = tid >> 5;
    const int kc = (tid & 31) * 8;

    for (int i = 0; i < 3; ++i) {
        int kbase = kq * 768 + i * 256;
        __syncthreads();
        #pragma unroll
        for (int kk2 = 0; kk2 < 8; ++kk2) {
            int k = kbase + kk2 * 32 + kk;
            float v = (k < kmax) ? W[(size_t)k * G_ + g0 + go] : 0.0f;
            lt[go][kk2 * 32 + kk] = v;
        }
        __syncthreads();
        uint32_t u0 = pk4fp8(lt[nn][kc + 0] * WSCALE, lt[nn][kc + 1] * WSCALE,
                             lt[nn][kc + 2] * WSCALE, lt[nn][kc + 3] * WSCALE);
        uint32_t u1 = pk4fp8(lt[nn][kc + 4] * WSCALE, lt[nn][kc + 5] * WSCALE,
                             lt[nn][kc + 6] * WSCALE, lt[nn][kc + 7] * WSCALE);
        *(u32x2*)&wt[(size_t)(n0 + nn) * K_TOT + kbase + kc] = (u32x2){u0, u1};
    }
}

// ---------------- GEMM: out[m, 0:512] = ce @ W' + bias (fp8 MFMA) -----------
// R24 champion (89.7 us total), byte-identical restore.
// BM=128, BN=128, BK=64, 512 threads (8 waves, 2x4 of 64x32), grid 512
// -> 2 blocks/CU.
//   A: global f32x4 (64B-coalesced) -> P/Q named regs (2-deep) ->
//      cvt_pk_fp8 -> swizzled ds_write_b32 x4.
//   B: fp8 wt via global_load_lds, 16B-granule source-preswizzled.
// Tiles 128 rows x 64 fp8 = 8KB each; LDS = 2*(8+8) = 32KB.
// Swizzle (16B granule): slot16 ^= (row>>1)&3; element k at byte
//   row*64 + (((k>>4)^((row>>1)&3))<<4) + (k&15).
// Counted vmcnt: 5 VMEM/phase (4 A + 1 B); WAITV(5) drains {B(t), A(t+1)}.
__global__ __launch_bounds__(512, 2) void gemm_kernel(
    const float* __restrict__ events, const float* __restrict__ contexts,
    const u8* __restrict__ wt, const float* __restrict__ bias,
    float* __restrict__ out)
{
    __shared__ u8 Ab[2][128 * 64];    // fp8 A tiles, swizzled (8 KB each)
    __shared__ u8 Bs[2][128 * 64];    // fp8 B tiles, swizzled (8 KB each)

    const int tid = threadIdx.x;
    const int bid = blockIdx.x;
    // 4 nb-blocks of an A panel share bid&7 -> same XCD.
    const int xx  = bid & 7;
    const int jj  = bid >> 3;            // 0..63
    const int nb  = jj & 3;
    const int mp  = (jj >> 2) * 8 + xx;  // 0..127
    const int m0  = mp * 128;

    const int lane = tid & 63;
    const int w    = tid >> 6;           // 0..7
    const int wm   = (w >> 2) * 64;      // 0 or 64
    const int wn   = (w & 3) * 32;       // 0,32,64,96
    const int lr   = lane & 15;
    const int kg   = lane >> 4;          // k-octet 0..3

    // ---- A staging: row r = tid>>2 (0..127), quarter q = tid&3 ----
    // Thread holds k = j*16 + q*4 .. +3 for j=0..3 (per-instr 64B/row coalesced)
    const int r = tid >> 2;
    const int q = tid & 3;
    int m = m0 + r; if (m > M_TOT - 1) m = M_TOT - 1;
    int bb = m / 1023;
    int tt = m - bb * 1023;
    const float* paE = events   + ((size_t)(bb * L_ + tt)) * H_;
    const float* paC = contexts + ((size_t)(bb * (L_ - 1) + tt)) * H_;
    // swizzled ds_write_b32 byte offsets
    int aw[4];
    #pragma unroll
    for (int j = 0; j < 4; ++j)
        aw[j] = r * 64 + (((j ^ ((r >> 1) & 3))) << 4) + q * 4;

    // ---- B staging: 1 gload16/thread, source-preswizzled (16B granule) ----
    const int bv   = tid >> 2;           // row 0..127
    const int bc   = tid & 3;            // dest slot16
    const int bcs  = bc ^ ((bv >> 1) & 3);
    const u8* bS = wt + (size_t)(nb * 128 + bv) * K_TOT + bcs * 16;

    // ---- fragment read offsets (bytes; element k = ks*32 + kg*8) ----
    int aoff[4][2], boff[2][2];
    #pragma unroll
    for (int i = 0; i < 4; ++i) {
        int row = wm + i * 16 + lr;
        #pragma unroll
        for (int ks = 0; ks < 2; ++ks) {
            int c16 = ks * 2 + (kg >> 1);
            aoff[i][ks] = row * 64 + ((c16 ^ ((row >> 1) & 3)) << 4) + (kg & 1) * 8;
        }
    }
    #pragma unroll
    for (int j = 0; j < 2; ++j) {
        int nn = wn + j * 16 + lr;
        #pragma unroll
        for (int ks = 0; ks < 2; ++ks) {
            int c16 = ks * 2 + (kg >> 1);
            boff[j][ks] = nn * 64 + ((c16 ^ ((nn >> 1) & 3)) << 4) + (kg & 1) * 8;
        }
    }

    f32x4 acc[4][2];
    #pragma unroll
    for (int i = 0; i < 4; ++i)
        #pragma unroll
        for (int j = 0; j < 2; ++j)
            acc[i][j] = (f32x4){0.f, 0.f, 0.f, 0.f};

    auto stageB = [&](int buf, int kt) {
        gload16(bS + kt * 64, &Bs[buf][tid * 16]);
    };
    auto compute = [&](int buf) {
        #pragma unroll
        for (int ks = 0; ks < 2; ++ks) {
            long a[4], bf[2];
            #pragma unroll
            for (int i = 0; i < 4; ++i)
                a[i] = *(const long*)&Ab[buf][aoff[i][ks]];
            #pragma unroll
            for (int j = 0; j < 2; ++j)
                bf[j] = *(const long*)&Bs[buf][boff[j][ks]];
            __builtin_amdgcn_s_setprio(1);
            #pragma unroll
            for (int i = 0; i < 4; ++i)
                #pragma unroll
                for (int j = 0; j < 2; ++j)
                    acc[i][j] = __builtin_amdgcn_mfma_f32_16x16x32_fp8_fp8(
                        a[i], bf[j], acc[i][j], 0, 0, 0);
            __builtin_amdgcn_s_setprio(0);
        }
    };

    // Named A-staging register sets (2-phase-deep; no arrays -> no scratch)
    f32x4 P0, P1, P2, P3;
    f32x4 Q0, Q1, Q2, Q3;

#define LOADA(p, KT)                                                           \
    {                                                                          \
        int k0_ = (KT) * 64;                                                   \
        int rg_ = (KT) >> 4;                                                   \
        int kq_ = (k0_ & 1023) + q * 4;                                        \
        const float* s_ = (rg_ == 0) ? paE : (rg_ == 1 ? (paE + H_) : paC);    \
        s_ += kq_;                                                             \
        p##0 = *(const f32x4*)(s_ +  0);                                       \
        p##1 = *(const f32x4*)(s_ + 16);                                       \
        p##2 = *(const f32x4*)(s_ + 32);                                       \
        p##3 = *(const f32x4*)(s_ + 48);                                       \
    }
#define CVT1(p, J, BUF)                                                        \
    {                                                                          \
        uint32_t w_ = pk4fp8(p##J[0], p##J[1], p##J[2], p##J[3]);              \
        *(uint32_t*)&Ab[BUF][aw[J]] = w_;                                      \
    }
#define CVTW(p, BUF)  CVT1(p, 0, BUF) CVT1(p, 1, BUF) CVT1(p, 2, BUF) CVT1(p, 3, BUF)

#define WAITV(N)                                                               \
    asm volatile("s_waitcnt vmcnt(" #N ")" ::: "memory");                      \
    __builtin_amdgcn_sched_barrier(0);
#define LGKM0                                                                  \
    asm volatile("s_waitcnt lgkmcnt(0)" ::: "memory");                         \
    __builtin_amdgcn_sched_barrier(0);
#define BAR __builtin_amdgcn_s_barrier()

    // prologue: A(0)->regs->Ab[0]; B(0) in flight; A(1)->Q (in flight)
    LOADA(P, 0);
    stageB(0, 0);
    WAITV(1);            // drain P = A(0) regs, leave B(0)
    CVTW(P, 0);
    LOADA(Q, 1);         // outstanding: B(0) 1 + Q 4 = 5
    LGKM0;               // prologue ds_writes done before first barrier

    for (int t = 0; t < 46; t += 2) {
        // phase t (buf0): consume Q=A(t+1) after WAITV
        LOADA(P, t + 2);
        stageB(1, t + 1);
        WAITV(5); BAR;                 // drains B(t) + Q regs
        compute(0);
        CVTW(Q, 1);
        LGKM0; BAR;
        // phase t+1 (buf1)
        LOADA(Q, t + 3);
        stageB(0, t + 2);
        WAITV(5); BAR;                 // drains B(t+1) + P regs
        compute(1);
        CVTW(P, 0);
        LGKM0; BAR;
    }
    // phase 46 (buf0): Q holds A(47); no more A loads
    stageB(1, 47);
    WAITV(1); BAR;                     // drains B(46) + Q regs, leaves B(47)
    compute(0);
    CVTW(Q, 1);
    LGKM0; BAR;
    // phase 47 (buf1)
    WAITV(0); BAR;
    compute(1);

#undef LOADA
#undef CVT1
#undef CVTW
#undef WAITV
#undef LGKM0
#undef BAR

    // epilogue: row = m0 + wm + i*16 + kg*4 + rr ; gcol = nb*128 + wn + j*16 + lr
    // un-scale W (x128) by WINV.
    const float* bptr = bias + nb * 128;
    float* obase = out + (size_t)nb * OUT_SEG;
    #pragma unroll
    for (int i = 0; i < 4; ++i) {
        int mloc = wm + i * 16 + kg * 4;
        #pragma unroll
        for (int j = 0; j < 2; ++j) {
            int g = wn + j * 16 + lr;
            float bv2 = bptr[g];
            #pragma unroll
            for (int rr = 0; rr < 4; ++rr) {
                int mo = m0 + mloc + rr;
                if (mo < M_TOT)
                    obase[(size_t)mo * G_ + g] = acc[i][j][rr] * WINV + bv2;
            }
        }
    }
}

// ---------------- KL reduction: stage 1 (f32x4 loads, 8 rows/block) ----------
__global__ __launch_bounds__(256) void kl_kernel(const float* __restrict__ out,
                                                 float* __restrict__ partial)
{
    int row  = blockIdx.x * 8 + (threadIdx.x >> 5);   // 2046*8 = M_TOT
    int col  = (threadIdx.x & 31) * 4;
    const float* zm  = out;
    const float* zlv = out + OUT_SEG;
    const float* qm  = out + (size_t)2 * OUT_SEG;
    const float* qlv = out + (size_t)3 * OUT_SEG;
    size_t base = (size_t)row * G_ + col;
    f32x4 a = *(const f32x4*)&zm[base];
    f32x4 b = *(const f32x4*)&zlv[base];
    f32x4 c = *(const f32x4*)&qm[base];
    f32x4 d = *(const f32x4*)&qlv[base];
    float s = 0.f;
    #pragma unroll
    for (int e = 0; e < 4; ++e) {
        float diff = a[e] - c[e];
        s += d[e] - b[e] + (__expf(b[e]) + diff * diff) * __expf(-d[e]) - 1.0f;
    }
    #pragma unroll
    for (int off = 32; off > 0; off >>= 1)
        s += __shfl_down(s, off);
    __shared__ float pw[4];
    int wid  = threadIdx.x >> 6;
    int lane = threadIdx.x & 63;
    if (lane == 0) pw[wid] = s;
    __syncthreads();
    if (threadIdx.x == 0)
        partial[blockIdx.x] = pw[0] + pw[1] + pw[2] + pw[3];
}

// ---------------- KL reduction: stage 2 --------------------------------------
__global__ __launch_bounds__(256) void kl_final(const float* __restrict__ partial,
                                                float* __restrict__ out)
{
    float s = 0.f;
    for (int i = threadIdx.x; i < KL_BLOCKS; i += 256) s += partial[i];
    #pragma unroll
    for (int off = 32; off > 0; off >>= 1)
        s += __shfl_down(s, off);
    __shared__ float pw[4];
    int wid = threadIdx.x >> 6;
    int lane = threadIdx.x & 63;
    if (lane == 0) pw[wid] = s;
    __syncthreads();
    if (threadIdx.x == 0)
        out[KL_IDX] = 0.5f * (pw[0] + pw[1] + pw[2] + pw[3]) / (float)M_TOT;
}

// ---------------- launcher ----------------------------------------------------
extern "C" void kernel_launch(void* const* d_in, const int* in_sizes, int n_in,
                              void* d_out, int out_size, void* d_ws, size_t ws_size,
                              hipStream_t stream)
{
    const float* events   = (const float*)d_in[0];
    const float* contexts = (const float*)d_in[1];
    const float* Wzm = (const float*)d_in[2];
    const float* bzm = (const float*)d_in[3];
    const float* Wzv = (const float*)d_in[4];
    const float* bzv = (const float*)d_in[5];
    const float* Wqm = (const float*)d_in[6];
    const float* bqm = (const float*)d_in[7];
    const float* Wqv = (const float*)d_in[8];
    const float* bqv = (const float*)d_in[9];
    float* out = (float*)d_out;

    u8*    wt      = (u8*)((char*)d_ws + WS_WT_OFF);
    float* bias    = (float*)((char*)d_ws + WS_BIAS_OFF);
    float* partial = (float*)((char*)d_ws + WS_PART_OFF);

    prep_kernel<<<256, 256, 0, stream>>>(Wzm, bzm, Wzv, bzv, Wqm, bqm, Wqv, bqv,
                                         wt, bias);
    gemm_kernel<<<512, 512, 0, stream>>>(events, contexts, wt, bias, out);
    kl_kernel<<<KL_BLOCKS, 256, 0, stream>>>(out, partial);
    kl_final<<<1, 256, 0, stream>>>(partial, out);
}

// Round 27
// 90.480 us; speedup vs baseline: 1.2729x; 1.0003x over previous
//
#include <hip/hip_runtime.h>
#include <stdint.h>

typedef unsigned char u8;
typedef unsigned short u16;
typedef __attribute__((ext_vector_type(8))) short short8;
typedef __attribute__((ext_vector_type(4))) float f32x4;
typedef __attribute__((ext_vector_type(2))) uint32_t u32x2;

#define B_      16
#define L_      1024
#define H_      1024
#define G_      128
#define M_TOT   16368            // B*(L-1)
#define K_TOT   3072
#define OUT_SEG 2095104          // M_TOT*G_
#define KL_IDX  (4*OUT_SEG)
#define KL_BLOCKS 2046           // M_TOT / 8 exactly
#define WSCALE  128.0f
#define WINV    0.0078125f       // 1/128

// ws layout
#define WS_WT_OFF    0           // fp8 W'T [512][3072] = 1,572,864 B
#define WS_BIAS_OFF  1572864     // float[512]
#define WS_PART_OFF  1574912     // float[2046] block partials

__device__ inline void gload16(const void* g, void* l) {
    __builtin_amdgcn_global_load_lds(
        (const __attribute__((address_space(1))) void*)g,
        (__attribute__((address_space(3))) void*)l, 16, 0, 0);
}

// pack 4 floats -> 4 fp8 (e4m3, OCP on gfx950) in one u32, k-ascending bytes
__device__ inline uint32_t pk4fp8(float f0, float f1, float f2, float f3) {
    uint32_t w = __builtin_amdgcn_cvt_pk_fp8_f32(f0, f1, 0, 0);
    w = __builtin_amdgcn_cvt_pk_fp8_f32(f2, f3, w, 1);
    return w;
}

// ---------------- prep: build W'T fp8 (x128) [512][3072] + bias[512] ---------
__global__ __launch_bounds__(256) void prep_kernel(
    const float* __restrict__ Wzm, const float* __restrict__ bzm,
    const float* __restrict__ Wzv, const float* __restrict__ bzv,
    const float* __restrict__ Wqm, const float* __restrict__ bqm,
    const float* __restrict__ Wqv, const float* __restrict__ bqv,
    u8* __restrict__ wt, float* __restrict__ bias)
{
    const int ng = blockIdx.x >> 2;
    const int kq = blockIdx.x & 3;
    const int n0 = ng * 8;
    const float* W; const float* bsrc; int g0; int kmax;
    if (n0 < 128)      { W = Wzm; bsrc = bzm; g0 = n0;       kmax = 2048; }
    else if (n0 < 256) { W = Wzv; bsrc = bzv; g0 = n0 - 128; kmax = 2048; }
    else if (n0 < 384) { W = Wqm; bsrc = bqm; g0 = n0 - 256; kmax = 3072; }
    else               { W = Wqv; bsrc = bqv; g0 = n0 - 384; kmax = 3072; }
    const int tid = threadIdx.x;
    if (kq == 0 && tid < 8) bias[n0 + tid] = bsrc[g0 + tid];

    __shared__ float lt[8][260];
    const int go = tid & 7;
    const int kk = tid >> 3;
    const int nn = tid >> 5;
    const int kc = (tid & 31) * 8;

    for (int i = 0; i < 3; ++i) {
        int kbase = kq * 768 + i * 256;
        __syncthreads();
        #pragma unroll
        for (int kk2 = 0; kk2 < 8; ++kk2) {
            int k = kbase + kk2 * 32 + kk;
            float v = (k < kmax) ? W[(size_t)k * G_ + g0 + go] : 0.0f;
            lt[go][kk2 * 32 + kk] = v;
        }
        __syncthreads();
        uint32_t u0 = pk4fp8(lt[nn][kc + 0] * WSCALE, lt[nn][kc + 1] * WSCALE,
                             lt[nn][kc + 2] * WSCALE, lt[nn][kc + 3] * WSCALE);
        uint32_t u1 = pk4fp8(lt[nn][kc + 4] * WSCALE, lt[nn][kc + 5] * WSCALE,
                             lt[nn][kc + 6] * WSCALE, lt[nn][kc + 7] * WSCALE);
        *(u32x2*)&wt[(size_t)(n0 + nn) * K_TOT + kbase + kc] = (u32x2){u0, u1};
    }
}

// ---------------- GEMM: out[m, 0:512] = ce @ W' + bias (fp8 MFMA) -----------
// Final champion (R24, 89.7 us total).
// BM=128, BN=128, BK=64, 512 threads (8 waves, 2x4 of 64x32), grid 512
// -> 2 blocks/CU.
//   A: global f32x4 (64B-coalesced) -> P/Q named regs (2-deep) ->
//      cvt_pk_fp8 -> swizzled ds_write_b32 x4.
//   B: fp8 wt via global_load_lds, 16B-granule source-preswizzled.
// Tiles 128 rows x 64 fp8 = 8KB each; LDS = 2*(8+8) = 32KB.
// Swizzle (16B granule): slot16 ^= (row>>1)&3; element k at byte
//   row*64 + (((k>>4)^((row>>1)&3))<<4) + (k&15).
// Counted vmcnt: 5 VMEM/phase (4 A + 1 B); WAITV(5) drains {B(t), A(t+1)}.
__global__ __launch_bounds__(512, 2) void gemm_kernel(
    const float* __restrict__ events, const float* __restrict__ contexts,
    const u8* __restrict__ wt, const float* __restrict__ bias,
    float* __restrict__ out)
{
    __shared__ u8 Ab[2][128 * 64];    // fp8 A tiles, swizzled (8 KB each)
    __shared__ u8 Bs[2][128 * 64];    // fp8 B tiles, swizzled (8 KB each)

    const int tid = threadIdx.x;
    const int bid = blockIdx.x;
    // 4 nb-blocks of an A panel share bid&7 -> same XCD.
    const int xx  = bid & 7;
    const int jj  = bid >> 3;            // 0..63
    const int nb  = jj & 3;
    const int mp  = (jj >> 2) * 8 + xx;  // 0..127
    const int m0  = mp * 128;

    const int lane = tid & 63;
    const int w    = tid >> 6;           // 0..7
    const int wm   = (w >> 2) * 64;      // 0 or 64
    const int wn   = (w & 3) * 32;       // 0,32,64,96
    const int lr   = lane & 15;
    const int kg   = lane >> 4;          // k-octet 0..3

    // ---- A staging: row r = tid>>2 (0..127), quarter q = tid&3 ----
    const int r = tid >> 2;
    const int q = tid & 3;
    int m = m0 + r; if (m > M_TOT - 1) m = M_TOT - 1;
    int bb = m / 1023;
    int tt = m - bb * 1023;
    const float* paE = events   + ((size_t)(bb * L_ + tt)) * H_;
    const float* paC = contexts + ((size_t)(bb * (L_ - 1) + tt)) * H_;
    // swizzled ds_write_b32 byte offsets
    int aw[4];
    #pragma unroll
    for (int j = 0; j < 4; ++j)
        aw[j] = r * 64 + (((j ^ ((r >> 1) & 3))) << 4) + q * 4;

    // ---- B staging: 1 gload16/thread, source-preswizzled (16B granule) ----
    const int bv   = tid >> 2;           // row 0..127
    const int bc   = tid & 3;            // dest slot16
    const int bcs  = bc ^ ((bv >> 1) & 3);
    const u8* bS = wt + (size_t)(nb * 128 + bv) * K_TOT + bcs * 16;

    // ---- fragment read offsets (bytes; element k = ks*32 + kg*8) ----
    int aoff[4][2], boff[2][2];
    #pragma unroll
    for (int i = 0; i < 4; ++i) {
        int row = wm + i * 16 + lr;
        #pragma unroll
        for (int ks = 0; ks < 2; ++ks) {
            int c16 = ks * 2 + (kg >> 1);
            aoff[i][ks] = row * 64 + ((c16 ^ ((row >> 1) & 3)) << 4) + (kg & 1) * 8;
        }
    }
    #pragma unroll
    for (int j = 0; j < 2; ++j) {
        int nn = wn + j * 16 + lr;
        #pragma unroll
        for (int ks = 0; ks < 2; ++ks) {
            int c16 = ks * 2 + (kg >> 1);
            boff[j][ks] = nn * 64 + ((c16 ^ ((nn >> 1) & 3)) << 4) + (kg & 1) * 8;
        }
    }

    f32x4 acc[4][2];
    #pragma unroll
    for (int i = 0; i < 4; ++i)
        #pragma unroll
        for (int j = 0; j < 2; ++j)
            acc[i][j] = (f32x4){0.f, 0.f, 0.f, 0.f};

    auto stageB = [&](int buf, int kt) {
        gload16(bS + kt * 64, &Bs[buf][tid * 16]);
    };
    auto compute = [&](int buf) {
        #pragma unroll
        for (int ks = 0; ks < 2; ++ks) {
            long a[4], bf[2];
            #pragma unroll
            for (int i = 0; i < 4; ++i)
                a[i] = *(const long*)&Ab[buf][aoff[i][ks]];
            #pragma unroll
            for (int j = 0; j < 2; ++j)
                bf[j] = *(const long*)&Bs[buf][boff[j][ks]];
            __builtin_amdgcn_s_setprio(1);
            #pragma unroll
            for (int i = 0; i < 4; ++i)
                #pragma unroll
                for (int j = 0; j < 2; ++j)
                    acc[i][j] = __builtin_amdgcn_mfma_f32_16x16x32_fp8_fp8(
                        a[i], bf[j], acc[i][j], 0, 0, 0);
            __builtin_amdgcn_s_setprio(0);
        }
    };

    // Named A-staging register sets (2-phase-deep; no arrays -> no scratch)
    f32x4 P0, P1, P2, P3;
    f32x4 Q0, Q1, Q2, Q3;

#define LOADA(p, KT)                                                           \
    {                                                                          \
        int k0_ = (KT) * 64;                                                   \
        int rg_ = (KT) >> 4;                                                   \
        int kq_ = (k0_ & 1023) + q * 4;                                        \
        const float* s_ = (rg_ == 0) ? paE : (rg_ == 1 ? (paE + H_) : paC);    \
        s_ += kq_;                                                             \
        p##0 = *(const f32x4*)(s_ +  0);                                       \
        p##1 = *(const f32x4*)(s_ + 16);                                       \
        p##2 = *(const f32x4*)(s_ + 32);                                       \
        p##3 = *(const f32x4*)(s_ + 48);                                       \
    }
#define CVT1(p, J, BUF)                                                        \
    {                                                                          \
        uint32_t w_ = pk4fp8(p##J[0], p##J[1], p##J[2], p##J[3]);              \
        *(uint32_t*)&Ab[BUF][aw[J]] = w_;                                      \
    }
#define CVTW(p, BUF)  CVT1(p, 0, BUF) CVT1(p, 1, BUF) CVT1(p, 2, BUF) CVT1(p, 3, BUF)

#define WAITV(N)                                                               \
    asm volatile("s_waitcnt vmcnt(" #N ")" ::: "memory");                      \
    __builtin_amdgcn_sched_barrier(0);
#define LGKM0                                                                  \
    asm volatile("s_waitcnt lgkmcnt(0)" ::: "memory");                         \
    __builtin_amdgcn_sched_barrier(0);
#define BAR __builtin_amdgcn_s_barrier()

    // prologue: A(0)->regs->Ab[0]; B(0) in flight; A(1)->Q (in flight)
    LOADA(P, 0);
    stageB(0, 0);
    WAITV(1);            // drain P = A(0) regs, leave B(0)
    CVTW(P, 0);
    LOADA(Q, 1);         // outstanding: B(0) 1 + Q 4 = 5
    LGKM0;               // prologue ds_writes done before first barrier

    for (int t = 0; t < 46; t += 2) {
        // phase t (buf0): consume Q=A(t+1) after WAITV
        LOADA(P, t + 2);
        stageB(1, t + 1);
        WAITV(5); BAR;                 // drains B(t) + Q regs
        compute(0);
        CVTW(Q, 1);
        LGKM0; BAR;
        // phase t+1 (buf1)
        LOADA(Q, t + 3);
        stageB(0, t + 2);
        WAITV(5); BAR;                 // drains B(t+1) + P regs
        compute(1);
        CVTW(P, 0);
        LGKM0; BAR;
    }
    // phase 46 (buf0): Q holds A(47); no more A loads
    stageB(1, 47);
    WAITV(1); BAR;                     // drains B(46) + Q regs, leaves B(47)
    compute(0);
    CVTW(Q, 1);
    LGKM0; BAR;
    // phase 47 (buf1)
    WAITV(0); BAR;
    compute(1);

#undef LOADA
#undef CVT1
#undef CVTW
#undef WAITV
#undef LGKM0
#undef BAR

    // epilogue: row = m0 + wm + i*16 + kg*4 + rr ; gcol = nb*128 + wn + j*16 + lr
    // un-scale W (x128) by WINV.
    const float* bptr = bias + nb * 128;
    float* obase = out + (size_t)nb * OUT_SEG;
    #pragma unroll
    for (int i = 0; i < 4; ++i) {
        int mloc = wm + i * 16 + kg * 4;
        #pragma unroll
        for (int j = 0; j < 2; ++j) {
            int g = wn + j * 16 + lr;
            float bv2 = bptr[g];
            #pragma unroll
            for (int rr = 0; rr < 4; ++rr) {
                int mo = m0 + mloc + rr;
                if (mo < M_TOT)
                    obase[(size_t)mo * G_ + g] = acc[i][j][rr] * WINV + bv2;
            }
        }
    }
}

// ---------------- KL reduction: stage 1 (f32x4 loads, 8 rows/block) ----------
__global__ __launch_bounds__(256) void kl_kernel(const float* __restrict__ out,
                                                 float* __restrict__ partial)
{
    int row  = blockIdx.x * 8 + (threadIdx.x >> 5);   // 2046*8 = M_TOT
    int col  = (threadIdx.x & 31) * 4;
    const float* zm  = out;
    const float* zlv = out + OUT_SEG;
    const float* qm  = out + (size_t)2 * OUT_SEG;
    const float* qlv = out + (size_t)3 * OUT_SEG;
    size_t base = (size_t)row * G_ + col;
    f32x4 a = *(const f32x4*)&zm[base];
    f32x4 b = *(const f32x4*)&zlv[base];
    f32x4 c = *(const f32x4*)&qm[base];
    f32x4 d = *(const f32x4*)&qlv[base];
    float s = 0.f;
    #pragma unroll
    for (int e = 0; e < 4; ++e) {
        float diff = a[e] - c[e];
        s += d[e] - b[e] + (__expf(b[e]) + diff * diff) * __expf(-d[e]) - 1.0f;
    }
    #pragma unroll
    for (int off = 32; off > 0; off >>= 1)
        s += __shfl_down(s, off);
    __shared__ float pw[4];
    int wid  = threadIdx.x >> 6;
    int lane = threadIdx.x & 63;
    if (lane == 0) pw[wid] = s;
    __syncthreads();
    if (threadIdx.x == 0)
        partial[blockIdx.x] = pw[0] + pw[1] + pw[2] + pw[3];
}

// ---------------- KL reduction: stage 2 --------------------------------------
__global__ __launch_bounds__(256) void kl_final(const float* __restrict__ partial,
                                                float* __restrict__ out)
{
    float s = 0.f;
    for (int i = threadIdx.x; i < KL_BLOCKS; i += 256) s += partial[i];
    #pragma unroll
    for (int off = 32; off > 0; off >>= 1)
        s += __shfl_down(s, off);
    __shared__ float pw[4];
    int wid = threadIdx.x >> 6;
    int lane = threadIdx.x & 63;
    if (lane == 0) pw[wid] = s;
    __syncthreads();
    if (threadIdx.x == 0)
        out[KL_IDX] = 0.5f * (pw[0] + pw[1] + pw[2] + pw[3]) / (float)M_TOT;
}

// ---------------- launcher ----------------------------------------------------
extern "C" void kernel_launch(void* const* d_in, const int* in_sizes, int n_in,
                              void* d_out, int out_size, void* d_ws, size_t ws_size,
                              hipStream_t stream)
{
    const float* events   = (const float*)d_in[0];
    const float* contexts = (const float*)d_in[1];
    const float* Wzm = (const float*)d_in[2];
    const float* bzm = (const float*)d_in[3];
    const float* Wzv = (const float*)d_in[4];
    const float* bzv = (const float*)d_in[5];
    const float* Wqm = (const float*)d_in[6];
    const float* bqm = (const float*)d_in[7];
    const float* Wqv = (const float*)d_in[8];
    const float* bqv = (const float*)d_in[9];
    float* out = (float*)d_out;

    u8*    wt      = (u8*)((char*)d_ws + WS_WT_OFF);
    float* bias    = (float*)((char*)d_ws + WS_BIAS_OFF);
    float* partial = (float*)((char*)d_ws + WS_PART_OFF);

    prep_kernel<<<256, 256, 0, stream>>>(Wzm, bzm, Wzv, bzv, Wqm, bqm, Wqv, bqv,
                                         wt, bias);
    gemm_kernel<<<512, 512, 0, stream>>>(events, contexts, wt, bias, out);
    kl_kernel<<<KL_BLOCKS, 256, 0, stream>>>(out, partial);
    kl_final<<<1, 256, 0, stream>>>(partial, out);
}

// Round 28
// 86.602 us; speedup vs baseline: 1.3299x; 1.0448x over previous
//
#include <hip/hip_runtime.h>
#include <stdint.h>

typedef unsigned char u8;
typedef unsigned short u16;
typedef __attribute__((ext_vector_type(4))) float f32x4;
typedef __attribute__((ext_vector_type(2))) uint32_t u32x2;

#define B_      16
#define L_      1024
#define H_      1024
#define G_      128
#define M_TOT   16368            // B*(L-1)
#define K_TOT   3072
#define OUT_SEG 2095104          // M_TOT*G_
#define KL_IDX  (4*OUT_SEG)
#define KL_PARTS 512             // one partial per gemm block
#define WSCALE  128.0f
#define WINV    0.0078125f       // 1/128

// ws layout
#define WS_WT_OFF    0           // fp8 W'T [512][3072] = 1,572,864 B
#define WS_BIAS_OFF  1572864     // float[512]
#define WS_PART_OFF  1574912     // float[512] block partials

__device__ inline void gload16(const void* g, void* l) {
    __builtin_amdgcn_global_load_lds(
        (const __attribute__((address_space(1))) void*)g,
        (__attribute__((address_space(3))) void*)l, 16, 0, 0);
}

// pack 4 floats -> 4 fp8 (e4m3, OCP on gfx950) in one u32, k-ascending bytes
__device__ inline uint32_t pk4fp8(float f0, float f1, float f2, float f3) {
    uint32_t w = __builtin_amdgcn_cvt_pk_fp8_f32(f0, f1, 0, 0);
    w = __builtin_amdgcn_cvt_pk_fp8_f32(f2, f3, w, 1);
    return w;
}

// ---------------- prep: build W'T fp8 (x128) [512][3072] + bias[512] ---------
__global__ __launch_bounds__(256) void prep_kernel(
    const float* __restrict__ Wzm, const float* __restrict__ bzm,
    const float* __restrict__ Wzv, const float* __restrict__ bzv,
    const float* __restrict__ Wqm, const float* __restrict__ bqm,
    const float* __restrict__ Wqv, const float* __restrict__ bqv,
    u8* __restrict__ wt, float* __restrict__ bias)
{
    const int ng = blockIdx.x >> 2;
    const int kq = blockIdx.x & 3;
    const int n0 = ng * 8;
    const float* W; const float* bsrc; int g0; int kmax;
    if (n0 < 128)      { W = Wzm; bsrc = bzm; g0 = n0;       kmax = 2048; }
    else if (n0 < 256) { W = Wzv; bsrc = bzv; g0 = n0 - 128; kmax = 2048; }
    else if (n0 < 384) { W = Wqm; bsrc = bqm; g0 = n0 - 256; kmax = 3072; }
    else               { W = Wqv; bsrc = bqv; g0 = n0 - 384; kmax = 3072; }
    const int tid = threadIdx.x;
    if (kq == 0 && tid < 8) bias[n0 + tid] = bsrc[g0 + tid];

    __shared__ float lt[8][260];
    const int go = tid & 7;
    const int kk = tid >> 3;
    const int nn = tid >> 5;
    const int kc = (tid & 31) * 8;

    for (int i = 0; i < 3; ++i) {
        int kbase = kq * 768 + i * 256;
        __syncthreads();
        #pragma unroll
        for (int kk2 = 0; kk2 < 8; ++kk2) {
            int k = kbase + kk2 * 32 + kk;
            float v = (k < kmax) ? W[(size_t)k * G_ + g0 + go] : 0.0f;
            lt[go][kk2 * 32 + kk] = v;
        }
        __syncthreads();
        uint32_t u0 = pk4fp8(lt[nn][kc + 0] * WSCALE, lt[nn][kc + 1] * WSCALE,
                             lt[nn][kc + 2] * WSCALE, lt[nn][kc + 3] * WSCALE);
        uint32_t u1 = pk4fp8(lt[nn][kc + 4] * WSCALE, lt[nn][kc + 5] * WSCALE,
                             lt[nn][kc + 6] * WSCALE, lt[nn][kc + 7] * WSCALE);
        *(u32x2*)&wt[(size_t)(n0 + nn) * K_TOT + kbase + kc] = (u32x2){u0, u1};
    }
}

// ---------------- GEMM + fused KL --------------------------------------------
// R24 champion K-loop, column remap for KL fusion:
//   local col lc (0..127) -> gcol = (lc>>5)*128 + nbg*32 + (lc&31)
// so each block owns g in [nbg*32, nbg*32+32) across ALL 4 output segments.
// After the epilogue stores (L2-hot), the block reads back its own 64KB,
// computes its KL partial (each (m,g) cell owned by exactly one block),
// reduces, writes partial[bid]. kl stage-1 kernel eliminated.
// BM=128, BN=128, BK=64, 512 threads (8 waves, 2x4 of 64x32), grid 512
// -> 2 blocks/CU. Counted vmcnt: 5 VMEM/phase; WAITV(5) drains {B(t),A(t+1)}.
__global__ __launch_bounds__(512, 2) void gemm_kernel(
    const float* __restrict__ events, const float* __restrict__ contexts,
    const u8* __restrict__ wt, const float* __restrict__ bias,
    float* __restrict__ out, float* __restrict__ partial)
{
    __shared__ u8 Ab[2][128 * 64];    // fp8 A tiles, swizzled (8 KB each)
    __shared__ u8 Bs[2][128 * 64];    // fp8 B tiles, swizzled (8 KB each)

    const int tid = threadIdx.x;
    const int bid = blockIdx.x;
    // 4 nbg-blocks of an A panel share bid&7 -> same XCD.
    const int xx  = bid & 7;
    const int jj  = bid >> 3;            // 0..63
    const int nbg = jj & 3;              // g-group 0..3 (32 g's per group)
    const int mp  = (jj >> 2) * 8 + xx;  // 0..127
    const int m0  = mp * 128;

    const int lane = tid & 63;
    const int w    = tid >> 6;           // 0..7
    const int wm   = (w >> 2) * 64;      // 0 or 64
    const int wn   = (w & 3) * 32;       // 0,32,64,96
    const int lr   = lane & 15;
    const int kg   = lane >> 4;          // k-octet 0..3

    // ---- A staging: row r = tid>>2 (0..127), quarter q = tid&3 ----
    const int r = tid >> 2;
    const int q = tid & 3;
    int m = m0 + r; if (m > M_TOT - 1) m = M_TOT - 1;
    int bb = m / 1023;
    int tt = m - bb * 1023;
    const float* paE = events   + ((size_t)(bb * L_ + tt)) * H_;
    const float* paC = contexts + ((size_t)(bb * (L_ - 1) + tt)) * H_;
    // swizzled ds_write_b32 byte offsets
    int aw[4];
    #pragma unroll
    for (int j = 0; j < 4; ++j)
        aw[j] = r * 64 + (((j ^ ((r >> 1) & 3))) << 4) + q * 4;

    // ---- B staging: 1 gload16/thread, source-preswizzled (16B granule) ----
    // local row bv (0..127) -> wt row (bv>>5)*128 + nbg*32 + (bv&31)
    const int bv   = tid >> 2;
    const int bc   = tid & 3;
    const int bcs  = bc ^ ((bv >> 1) & 3);
    const int bwr  = (bv >> 5) * 128 + nbg * 32 + (bv & 31);
    const u8* bS = wt + (size_t)bwr * K_TOT + bcs * 16;

    // ---- fragment read offsets (bytes; element k = ks*32 + kg*8) ----
    int aoff[4][2], boff[2][2];
    #pragma unroll
    for (int i = 0; i < 4; ++i) {
        int row = wm + i * 16 + lr;
        #pragma unroll
        for (int ks = 0; ks < 2; ++ks) {
            int c16 = ks * 2 + (kg >> 1);
            aoff[i][ks] = row * 64 + ((c16 ^ ((row >> 1) & 3)) << 4) + (kg & 1) * 8;
        }
    }
    #pragma unroll
    for (int j = 0; j < 2; ++j) {
        int nn = wn + j * 16 + lr;
        #pragma unroll
        for (int ks = 0; ks < 2; ++ks) {
            int c16 = ks * 2 + (kg >> 1);
            boff[j][ks] = nn * 64 + ((c16 ^ ((nn >> 1) & 3)) << 4) + (kg & 1) * 8;
        }
    }

    f32x4 acc[4][2];
    #pragma unroll
    for (int i = 0; i < 4; ++i)
        #pragma unroll
        for (int j = 0; j < 2; ++j)
            acc[i][j] = (f32x4){0.f, 0.f, 0.f, 0.f};

    auto stageB = [&](int buf, int kt) {
        gload16(bS + kt * 64, &Bs[buf][tid * 16]);
    };
    auto compute = [&](int buf) {
        #pragma unroll
        for (int ks = 0; ks < 2; ++ks) {
            long a[4], bf[2];
            #pragma unroll
            for (int i = 0; i < 4; ++i)
                a[i] = *(const long*)&Ab[buf][aoff[i][ks]];
            #pragma unroll
            for (int j = 0; j < 2; ++j)
                bf[j] = *(const long*)&Bs[buf][boff[j][ks]];
            __builtin_amdgcn_s_setprio(1);
            #pragma unroll
            for (int i = 0; i < 4; ++i)
                #pragma unroll
                for (int j = 0; j < 2; ++j)
                    acc[i][j] = __builtin_amdgcn_mfma_f32_16x16x32_fp8_fp8(
                        a[i], bf[j], acc[i][j], 0, 0, 0);
            __builtin_amdgcn_s_setprio(0);
        }
    };

    // Named A-staging register sets (2-phase-deep; no arrays -> no scratch)
    f32x4 P0, P1, P2, P3;
    f32x4 Q0, Q1, Q2, Q3;

#define LOADA(p, KT)                                                           \
    {                                                                          \
        int k0_ = (KT) * 64;                                                   \
        int rg_ = (KT) >> 4;                                                   \
        int kq_ = (k0_ & 1023) + q * 4;                                        \
        const float* s_ = (rg_ == 0) ? paE : (rg_ == 1 ? (paE + H_) : paC);    \
        s_ += kq_;                                                             \
        p##0 = *(const f32x4*)(s_ +  0);                                       \
        p##1 = *(const f32x4*)(s_ + 16);                                       \
        p##2 = *(const f32x4*)(s_ + 32);                                       \
        p##3 = *(const f32x4*)(s_ + 48);                                       \
    }
#define CVT1(p, J, BUF)                                                        \
    {                                                                          \
        uint32_t w_ = pk4fp8(p##J[0], p##J[1], p##J[2], p##J[3]);              \
        *(uint32_t*)&Ab[BUF][aw[J]] = w_;                                      \
    }
#define CVTW(p, BUF)  CVT1(p, 0, BUF) CVT1(p, 1, BUF) CVT1(p, 2, BUF) CVT1(p, 3, BUF)

#define WAITV(N)                                                               \
    asm volatile("s_waitcnt vmcnt(" #N ")" ::: "memory");                      \
    __builtin_amdgcn_sched_barrier(0);
#define LGKM0                                                                  \
    asm volatile("s_waitcnt lgkmcnt(0)" ::: "memory");                         \
    __builtin_amdgcn_sched_barrier(0);
#define BAR __builtin_amdgcn_s_barrier()

    // prologue: A(0)->regs->Ab[0]; B(0) in flight; A(1)->Q (in flight)
    LOADA(P, 0);
    stageB(0, 0);
    WAITV(1);            // drain P = A(0) regs, leave B(0)
    CVTW(P, 0);
    LOADA(Q, 1);         // outstanding: B(0) 1 + Q 4 = 5
    LGKM0;               // prologue ds_writes done before first barrier

    for (int t = 0; t < 46; t += 2) {
        // phase t (buf0): consume Q=A(t+1) after WAITV
        LOADA(P, t + 2);
        stageB(1, t + 1);
        WAITV(5); BAR;                 // drains B(t) + Q regs
        compute(0);
        CVTW(Q, 1);
        LGKM0; BAR;
        // phase t+1 (buf1)
        LOADA(Q, t + 3);
        stageB(0, t + 2);
        WAITV(5); BAR;                 // drains B(t+1) + P regs
        compute(1);
        CVTW(P, 0);
        LGKM0; BAR;
    }
    // phase 46 (buf0): Q holds A(47); no more A loads
    stageB(1, 47);
    WAITV(1); BAR;                     // drains B(46) + Q regs, leaves B(47)
    compute(0);
    CVTW(Q, 1);
    LGKM0; BAR;
    // phase 47 (buf1)
    WAITV(0); BAR;
    compute(1);

    // ---- epilogue stores: lcol = wn + j*16 + lr -> seg = lcol>>5,
    //      gc = nbg*32 + (lcol&31); un-scale W (x128) by WINV. ----
    #pragma unroll
    for (int i = 0; i < 4; ++i) {
        int mloc = wm + i * 16 + kg * 4;
        #pragma unroll
        for (int j = 0; j < 2; ++j) {
            int lcol = wn + j * 16 + lr;
            int seg  = lcol >> 5;
            int gc   = nbg * 32 + (lcol & 31);
            float bv2 = bias[seg * 128 + gc];
            float* ob = out + (size_t)seg * OUT_SEG + gc;
            #pragma unroll
            for (int rr = 0; rr < 4; ++rr) {
                int mo = m0 + mloc + rr;
                if (mo < M_TOT)
                    ob[(size_t)mo * G_] = acc[i][j][rr] * WINV + bv2;
            }
        }
    }

    // ---- fused KL: read back this block's own cells (L2-hot) ----
    // thread (r, q): row m0+r, g-octet nbg*32 + q*8 .. +7
    WAITV(0); BAR;                     // all stores of this block visible
    float s = 0.f;
    {
        int mo = m0 + r;
        if (mo < M_TOT) {
            size_t base = (size_t)mo * G_ + nbg * 32 + q * 8;
            const float* p0 = out + base;                        // zm
            const float* p1 = out + OUT_SEG + base;              // zlv
            const float* p2 = out + (size_t)2 * OUT_SEG + base;  // qm
            const float* p3 = out + (size_t)3 * OUT_SEG + base;  // qlv
            #pragma unroll
            for (int h = 0; h < 2; ++h) {
                f32x4 av = *(const f32x4*)(p0 + h * 4);
                f32x4 bv = *(const f32x4*)(p1 + h * 4);
                f32x4 cv = *(const f32x4*)(p2 + h * 4);
                f32x4 dv = *(const f32x4*)(p3 + h * 4);
                #pragma unroll
                for (int e = 0; e < 4; ++e) {
                    float diff = av[e] - cv[e];
                    s += dv[e] - bv[e]
                       + (__expf(bv[e]) + diff * diff) * __expf(-dv[e]) - 1.0f;
                }
            }
        }
    }
    #pragma unroll
    for (int off = 32; off > 0; off >>= 1)
        s += __shfl_down(s, off);
    __shared__ float pw[8];
    if (lane == 0) pw[w] = s;
    BAR;
    LGKM0;
    if (tid == 0) {
        float t2 = 0.f;
        #pragma unroll
        for (int i = 0; i < 8; ++i) t2 += pw[i];
        partial[bid] = t2;
    }

#undef LOADA
#undef CVT1
#undef CVTW
#undef WAITV
#undef LGKM0
#undef BAR
}

// ---------------- KL final: reduce 512 block partials ------------------------
__global__ __launch_bounds__(256) void kl_final(const float* __restrict__ partial,
                                                float* __restrict__ out)
{
    float s = 0.f;
    for (int i = threadIdx.x; i < KL_PARTS; i += 256) s += partial[i];
    #pragma unroll
    for (int off = 32; off > 0; off >>= 1)
        s += __shfl_down(s, off);
    __shared__ float pw[4];
    int wid = threadIdx.x >> 6;
    int lane = threadIdx.x & 63;
    if (lane == 0) pw[wid] = s;
    __syncthreads();
    if (threadIdx.x == 0)
        out[KL_IDX] = 0.5f * (pw[0] + pw[1] + pw[2] + pw[3]) / (float)M_TOT;
}

// ---------------- launcher ----------------------------------------------------
extern "C" void kernel_launch(void* const* d_in, const int* in_sizes, int n_in,
                              void* d_out, int out_size, void* d_ws, size_t ws_size,
                              hipStream_t stream)
{
    const float* events   = (const float*)d_in[0];
    const float* contexts = (const float*)d_in[1];
    const float* Wzm = (const float*)d_in[2];
    const float* bzm = (const float*)d_in[3];
    const float* Wzv = (const float*)d_in[4];
    const float* bzv = (const float*)d_in[5];
    const float* Wqm = (const float*)d_in[6];
    const float* bqm = (const float*)d_in[7];
    const float* Wqv = (const float*)d_in[8];
    const float* bqv = (const float*)d_in[9];
    float* out = (float*)d_out;

    u8*    wt      = (u8*)((char*)d_ws + WS_WT_OFF);
    float* bias    = (float*)((char*)d_ws + WS_BIAS_OFF);
    float* partial = (float*)((char*)d_ws + WS_PART_OFF);

    prep_kernel<<<256, 256, 0, stream>>>(Wzm, bzm, Wzv, bzv, Wqm, bqm, Wqv, bqv,
                                         wt, bias);
    gemm_kernel<<<512, 512, 0, stream>>>(events, contexts, wt, bias, out, partial);
    kl_final<<<1, 256, 0, stream>>>(partial, out);
}

// Round 29
// 81.647 us; speedup vs baseline: 1.4106x; 1.0607x over previous
//
#include <hip/hip_runtime.h>
#include <stdint.h>

typedef unsigned char u8;
typedef unsigned short u16;
typedef __attribute__((ext_vector_type(4))) float f32x4;
typedef __attribute__((ext_vector_type(2))) uint32_t u32x2;

#define B_      16
#define L_      1024
#define H_      1024
#define G_      128
#define M_TOT   16368            // B*(L-1)
#define K_TOT   3072
#define OUT_SEG 2095104          // M_TOT*G_
#define KL_IDX  (4*OUT_SEG)
#define KL_PARTS 512             // one partial per gemm block
#define WSCALE  128.0f
#define WINV    0.0078125f       // 1/128

// ws layout
#define WS_WT_OFF    0           // fp8 W'T [512][3072] = 1,572,864 B
#define WS_BIAS_OFF  1572864     // float[512]
#define WS_PART_OFF  1574912     // float[512] block partials

__device__ inline void gload16(const void* g, void* l) {
    __builtin_amdgcn_global_load_lds(
        (const __attribute__((address_space(1))) void*)g,
        (__attribute__((address_space(3))) void*)l, 16, 0, 0);
}

// pack 4 floats -> 4 fp8 (e4m3, OCP on gfx950) in one u32, k-ascending bytes
__device__ inline uint32_t pk4fp8(float f0, float f1, float f2, float f3) {
    uint32_t w = __builtin_amdgcn_cvt_pk_fp8_f32(f0, f1, 0, 0);
    w = __builtin_amdgcn_cvt_pk_fp8_f32(f2, f3, w, 1);
    return w;
}

// ---------------- prep: build W'T fp8 (x128) [512][3072] + bias[512] ---------
__global__ __launch_bounds__(256) void prep_kernel(
    const float* __restrict__ Wzm, const float* __restrict__ bzm,
    const float* __restrict__ Wzv, const float* __restrict__ bzv,
    const float* __restrict__ Wqm, const float* __restrict__ bqm,
    const float* __restrict__ Wqv, const float* __restrict__ bqv,
    u8* __restrict__ wt, float* __restrict__ bias)
{
    const int ng = blockIdx.x >> 2;
    const int kq = blockIdx.x & 3;
    const int n0 = ng * 8;
    const float* W; const float* bsrc; int g0; int kmax;
    if (n0 < 128)      { W = Wzm; bsrc = bzm; g0 = n0;       kmax = 2048; }
    else if (n0 < 256) { W = Wzv; bsrc = bzv; g0 = n0 - 128; kmax = 2048; }
    else if (n0 < 384) { W = Wqm; bsrc = bqm; g0 = n0 - 256; kmax = 3072; }
    else               { W = Wqv; bsrc = bqv; g0 = n0 - 384; kmax = 3072; }
    const int tid = threadIdx.x;
    if (kq == 0 && tid < 8) bias[n0 + tid] = bsrc[g0 + tid];

    __shared__ float lt[8][260];
    const int go = tid & 7;
    const int kk = tid >> 3;
    const int nn = tid >> 5;
    const int kc = (tid & 31) * 8;

    for (int i = 0; i < 3; ++i) {
        int kbase = kq * 768 + i * 256;
        __syncthreads();
        #pragma unroll
        for (int kk2 = 0; kk2 < 8; ++kk2) {
            int k = kbase + kk2 * 32 + kk;
            float v = (k < kmax) ? W[(size_t)k * G_ + g0 + go] : 0.0f;
            lt[go][kk2 * 32 + kk] = v;
        }
        __syncthreads();
        uint32_t u0 = pk4fp8(lt[nn][kc + 0] * WSCALE, lt[nn][kc + 1] * WSCALE,
                             lt[nn][kc + 2] * WSCALE, lt[nn][kc + 3] * WSCALE);
        uint32_t u1 = pk4fp8(lt[nn][kc + 4] * WSCALE, lt[nn][kc + 5] * WSCALE,
                             lt[nn][kc + 6] * WSCALE, lt[nn][kc + 7] * WSCALE);
        *(u32x2*)&wt[(size_t)(n0 + nn) * K_TOT + kbase + kc] = (u32x2){u0, u1};
    }
}

// ---------------- GEMM + fused KL (LDS bounce, no global readback) -----------
// R24 champion K-loop. Column remap: local col lc -> gcol =
// (lc>>5)*128 + nbg*32 + (lc&31): block owns g in [nbg*32, nbg*32+32)
// across ALL 4 output segments -> the KL quadruple for each owned (m,g)
// is in the block's registers. Epilogue (2 chunks of 64 rows): waves
// write v = acc*WINV+bias to global AND to klbuf[64][132]; lgkm+barrier;
// each thread reads 4 quadruples from klbuf and accumulates the KL sum.
// No store-drain, no global readback. partial[bid] per block.
__global__ __launch_bounds__(512, 2) void gemm_kernel(
    const float* __restrict__ events, const float* __restrict__ contexts,
    const u8* __restrict__ wt, const float* __restrict__ bias,
    float* __restrict__ out, float* __restrict__ partial)
{
    __shared__ u8 Ab[2][128 * 64];    // fp8 A tiles, swizzled (8 KB each)
    __shared__ u8 Bs[2][128 * 64];    // fp8 B tiles, swizzled (8 KB each)
    __shared__ float klbuf[64 * 132]; // KL bounce buffer (33.8 KB)
    __shared__ float pw[8];

    const int tid = threadIdx.x;
    const int bid = blockIdx.x;
    // 4 nbg-blocks of an A panel share bid&7 -> same XCD.
    const int xx  = bid & 7;
    const int jj  = bid >> 3;            // 0..63
    const int nbg = jj & 3;              // g-group 0..3 (32 g's per group)
    const int mp  = (jj >> 2) * 8 + xx;  // 0..127
    const int m0  = mp * 128;

    const int lane = tid & 63;
    const int w    = tid >> 6;           // 0..7
    const int wm   = (w >> 2) * 64;      // 0 or 64
    const int wn   = (w & 3) * 32;       // 0,32,64,96
    const int lr   = lane & 15;
    const int kg   = lane >> 4;          // k-octet 0..3

    // ---- A staging: row r = tid>>2 (0..127), quarter q = tid&3 ----
    const int r = tid >> 2;
    const int q = tid & 3;
    int m = m0 + r; if (m > M_TOT - 1) m = M_TOT - 1;
    int bb = m / 1023;
    int tt = m - bb * 1023;
    const float* paE = events   + ((size_t)(bb * L_ + tt)) * H_;
    const float* paC = contexts + ((size_t)(bb * (L_ - 1) + tt)) * H_;
    // swizzled ds_write_b32 byte offsets
    int aw[4];
    #pragma unroll
    for (int j = 0; j < 4; ++j)
        aw[j] = r * 64 + (((j ^ ((r >> 1) & 3))) << 4) + q * 4;

    // ---- B staging: 1 gload16/thread, source-preswizzled (16B granule) ----
    // local row bv (0..127) -> wt row (bv>>5)*128 + nbg*32 + (bv&31)
    const int bv   = tid >> 2;
    const int bc   = tid & 3;
    const int bcs  = bc ^ ((bv >> 1) & 3);
    const int bwr  = (bv >> 5) * 128 + nbg * 32 + (bv & 31);
    const u8* bS = wt + (size_t)bwr * K_TOT + bcs * 16;

    // ---- fragment read offsets (bytes; element k = ks*32 + kg*8) ----
    int aoff[4][2], boff[2][2];
    #pragma unroll
    for (int i = 0; i < 4; ++i) {
        int row = wm + i * 16 + lr;
        #pragma unroll
        for (int ks = 0; ks < 2; ++ks) {
            int c16 = ks * 2 + (kg >> 1);
            aoff[i][ks] = row * 64 + ((c16 ^ ((row >> 1) & 3)) << 4) + (kg & 1) * 8;
        }
    }
    #pragma unroll
    for (int j = 0; j < 2; ++j) {
        int nn = wn + j * 16 + lr;
        #pragma unroll
        for (int ks = 0; ks < 2; ++ks) {
            int c16 = ks * 2 + (kg >> 1);
            boff[j][ks] = nn * 64 + ((c16 ^ ((nn >> 1) & 3)) << 4) + (kg & 1) * 8;
        }
    }

    f32x4 acc[4][2];
    #pragma unroll
    for (int i = 0; i < 4; ++i)
        #pragma unroll
        for (int j = 0; j < 2; ++j)
            acc[i][j] = (f32x4){0.f, 0.f, 0.f, 0.f};

    auto stageB = [&](int buf, int kt) {
        gload16(bS + kt * 64, &Bs[buf][tid * 16]);
    };
    auto compute = [&](int buf) {
        #pragma unroll
        for (int ks = 0; ks < 2; ++ks) {
            long a[4], bf[2];
            #pragma unroll
            for (int i = 0; i < 4; ++i)
                a[i] = *(const long*)&Ab[buf][aoff[i][ks]];
            #pragma unroll
            for (int j = 0; j < 2; ++j)
                bf[j] = *(const long*)&Bs[buf][boff[j][ks]];
            __builtin_amdgcn_s_setprio(1);
            #pragma unroll
            for (int i = 0; i < 4; ++i)
                #pragma unroll
                for (int j = 0; j < 2; ++j)
                    acc[i][j] = __builtin_amdgcn_mfma_f32_16x16x32_fp8_fp8(
                        a[i], bf[j], acc[i][j], 0, 0, 0);
            __builtin_amdgcn_s_setprio(0);
        }
    };

    // Named A-staging register sets (2-phase-deep; no arrays -> no scratch)
    f32x4 P0, P1, P2, P3;
    f32x4 Q0, Q1, Q2, Q3;

#define LOADA(p, KT)                                                           \
    {                                                                          \
        int k0_ = (KT) * 64;                                                   \
        int rg_ = (KT) >> 4;                                                   \
        int kq_ = (k0_ & 1023) + q * 4;                                        \
        const float* s_ = (rg_ == 0) ? paE : (rg_ == 1 ? (paE + H_) : paC);    \
        s_ += kq_;                                                             \
        p##0 = *(const f32x4*)(s_ +  0);                                       \
        p##1 = *(const f32x4*)(s_ + 16);                                       \
        p##2 = *(const f32x4*)(s_ + 32);                                       \
        p##3 = *(const f32x4*)(s_ + 48);                                       \
    }
#define CVT1(p, J, BUF)                                                        \
    {                                                                          \
        uint32_t w_ = pk4fp8(p##J[0], p##J[1], p##J[2], p##J[3]);              \
        *(uint32_t*)&Ab[BUF][aw[J]] = w_;                                      \
    }
#define CVTW(p, BUF)  CVT1(p, 0, BUF) CVT1(p, 1, BUF) CVT1(p, 2, BUF) CVT1(p, 3, BUF)

#define WAITV(N)                                                               \
    asm volatile("s_waitcnt vmcnt(" #N ")" ::: "memory");                      \
    __builtin_amdgcn_sched_barrier(0);
#define LGKM0                                                                  \
    asm volatile("s_waitcnt lgkmcnt(0)" ::: "memory");                         \
    __builtin_amdgcn_sched_barrier(0);
#define BAR __builtin_amdgcn_s_barrier()

    // prologue: A(0)->regs->Ab[0]; B(0) in flight; A(1)->Q (in flight)
    LOADA(P, 0);
    stageB(0, 0);
    WAITV(1);            // drain P = A(0) regs, leave B(0)
    CVTW(P, 0);
    LOADA(Q, 1);         // outstanding: B(0) 1 + Q 4 = 5
    LGKM0;               // prologue ds_writes done before first barrier

    for (int t = 0; t < 46; t += 2) {
        // phase t (buf0): consume Q=A(t+1) after WAITV
        LOADA(P, t + 2);
        stageB(1, t + 1);
        WAITV(5); BAR;                 // drains B(t) + Q regs
        compute(0);
        CVTW(Q, 1);
        LGKM0; BAR;
        // phase t+1 (buf1)
        LOADA(Q, t + 3);
        stageB(0, t + 2);
        WAITV(5); BAR;                 // drains B(t+1) + P regs
        compute(1);
        CVTW(P, 0);
        LGKM0; BAR;
    }
    // phase 46 (buf0): Q holds A(47); no more A loads
    stageB(1, 47);
    WAITV(1); BAR;                     // drains B(46) + Q regs, leaves B(47)
    compute(0);
    CVTW(Q, 1);
    LGKM0; BAR;
    // phase 47 (buf1)
    WAITV(0); BAR;
    compute(1);

    // ---- epilogue + fused KL via LDS bounce --------------------------------
    // chunk c covers local rows [32c, 32c+32) of each wm-half:
    //   writer i in {2c, 2c+1}; klbuf lrow = (wm>>1) + (i&1)*16 + kg*4 + rr
    // reader: lrow = tid>>3 (0..63), g-quad gq = (tid&7)*4;
    //   mo = m0 + (lrow&32 ? 64 : 0) + 32c + (lrow&31)
    float s = 0.f;
    #pragma unroll
    for (int c = 0; c < 2; ++c) {
        #pragma unroll
        for (int di = 0; di < 2; ++di) {
            int i = 2 * c + di;
            int mloc = wm + i * 16 + kg * 4;
            int lrb  = (wm >> 1) + di * 16 + kg * 4;
            #pragma unroll
            for (int j = 0; j < 2; ++j) {
                int lcol = wn + j * 16 + lr;
                int seg  = lcol >> 5;
                int gc   = nbg * 32 + (lcol & 31);
                float bv2 = bias[seg * 128 + gc];
                float* ob = out + (size_t)seg * OUT_SEG + gc;
                #pragma unroll
                for (int rr = 0; rr < 4; ++rr) {
                    int mo = m0 + mloc + rr;
                    float v = acc[i][j][rr] * WINV + bv2;
                    if (mo < M_TOT) ob[(size_t)mo * G_] = v;
                    klbuf[(lrb + rr) * 132 + lcol] = v;
                }
            }
        }
        LGKM0; BAR;                    // klbuf chunk visible block-wide
        {
            int lrow = tid >> 3;
            int gq   = (tid & 7) * 4;
            int mo2  = m0 + ((lrow & 32) ? 64 : 0) + 32 * c + (lrow & 31);
            if (mo2 < M_TOT) {
                const float* kb = klbuf + lrow * 132 + gq;
                f32x4 av = *(const f32x4*)(kb +  0);   // zm
                f32x4 bv = *(const f32x4*)(kb + 32);   // zlv
                f32x4 cv = *(const f32x4*)(kb + 64);   // qm
                f32x4 dv = *(const f32x4*)(kb + 96);   // qlv
                #pragma unroll
                for (int e = 0; e < 4; ++e) {
                    float diff = av[e] - cv[e];
                    s += dv[e] - bv[e]
                       + (__expf(bv[e]) + diff * diff) * __expf(-dv[e]) - 1.0f;
                }
            }
        }
        LGKM0; BAR;                    // reads done before next chunk rewrite
    }
    #pragma unroll
    for (int off = 32; off > 0; off >>= 1)
        s += __shfl_down(s, off);
    if (lane == 0) pw[w] = s;
    LGKM0; BAR;
    if (tid == 0) {
        float t2 = 0.f;
        #pragma unroll
        for (int i = 0; i < 8; ++i) t2 += pw[i];
        partial[bid] = t2;
    }

#undef LOADA
#undef CVT1
#undef CVTW
#undef WAITV
#undef LGKM0
#undef BAR
}

// ---------------- KL final: reduce 512 block partials ------------------------
__global__ __launch_bounds__(256) void kl_final(const float* __restrict__ partial,
                                                float* __restrict__ out)
{
    float s = 0.f;
    for (int i = threadIdx.x; i < KL_PARTS; i += 256) s += partial[i];
    #pragma unroll
    for (int off = 32; off > 0; off >>= 1)
        s += __shfl_down(s, off);
    __shared__ float pw[4];
    int wid = threadIdx.x >> 6;
    int lane = threadIdx.x & 63;
    if (lane == 0) pw[wid] = s;
    __syncthreads();
    if (threadIdx.x == 0)
        out[KL_IDX] = 0.5f * (pw[0] + pw[1] + pw[2] + pw[3]) / (float)M_TOT;
}

// ---------------- launcher ----------------------------------------------------
extern "C" void kernel_launch(void* const* d_in, const int* in_sizes, int n_in,
                              void* d_out, int out_size, void* d_ws, size_t ws_size,
                              hipStream_t stream)
{
    const float* events   = (const float*)d_in[0];
    const float* contexts = (const float*)d_in[1];
    const float* Wzm = (const float*)d_in[2];
    const float* bzm = (const float*)d_in[3];
    const float* Wzv = (const float*)d_in[4];
    const float* bzv = (const float*)d_in[5];
    const float* Wqm = (const float*)d_in[6];
    const float* bqm = (const float*)d_in[7];
    const float* Wqv = (const float*)d_in[8];
    const float* bqv = (const float*)d_in[9];
    float* out = (float*)d_out;

    u8*    wt      = (u8*)((char*)d_ws + WS_WT_OFF);
    float* bias    = (float*)((char*)d_ws + WS_BIAS_OFF);
    float* partial = (float*)((char*)d_ws + WS_PART_OFF);

    prep_kernel<<<256, 256, 0, stream>>>(Wzm, bzm, Wzv, bzv, Wqm, bqm, Wqv, bqv,
                                         wt, bias);
    gemm_kernel<<<512, 512, 0, stream>>>(events, contexts, wt, bias, out, partial);
    kl_final<<<1, 256, 0, stream>>>(partial, out);
}

// Round 30
// 81.513 us; speedup vs baseline: 1.4129x; 1.0016x over previous
//
#include <hip/hip_runtime.h>
#include <stdint.h>

typedef unsigned char u8;
typedef unsigned short u16;
typedef __attribute__((ext_vector_type(4))) float f32x4;
typedef __attribute__((ext_vector_type(2))) uint32_t u32x2;

#define B_      16
#define L_      1024
#define H_      1024
#define G_      128
#define M_TOT   16368            // B*(L-1)
#define K_TOT   3072
#define OUT_SEG 2095104          // M_TOT*G_
#define KL_IDX  (4*OUT_SEG)
#define KL_PARTS 512             // one partial per gemm block
#define WSCALE  128.0f
#define WINV    0.0078125f       // 1/128

// ws layout
#define WS_WT_OFF    0           // fp8 W'T [512][3072] = 1,572,864 B
#define WS_BIAS_OFF  1572864     // float[512]
#define WS_PART_OFF  1574912     // float[512] block partials

__device__ inline void gload16(const void* g, void* l) {
    __builtin_amdgcn_global_load_lds(
        (const __attribute__((address_space(1))) void*)g,
        (__attribute__((address_space(3))) void*)l, 16, 0, 0);
}

// pack 4 floats -> 4 fp8 (e4m3, OCP on gfx950) in one u32, k-ascending bytes
__device__ inline uint32_t pk4fp8(float f0, float f1, float f2, float f3) {
    uint32_t w = __builtin_amdgcn_cvt_pk_fp8_f32(f0, f1, 0, 0);
    w = __builtin_amdgcn_cvt_pk_fp8_f32(f2, f3, w, 1);
    return w;
}

// ---------------- prep: build W'T fp8 (x128) [512][3072] + bias[512] ---------
__global__ __launch_bounds__(256) void prep_kernel(
    const float* __restrict__ Wzm, const float* __restrict__ bzm,
    const float* __restrict__ Wzv, const float* __restrict__ bzv,
    const float* __restrict__ Wqm, const float* __restrict__ bqm,
    const float* __restrict__ Wqv, const float* __restrict__ bqv,
    u8* __restrict__ wt, float* __restrict__ bias)
{
    const int ng = blockIdx.x >> 2;
    const int kq = blockIdx.x & 3;
    const int n0 = ng * 8;
    const float* W; const float* bsrc; int g0; int kmax;
    if (n0 < 128)      { W = Wzm; bsrc = bzm; g0 = n0;       kmax = 2048; }
    else if (n0 < 256) { W = Wzv; bsrc = bzv; g0 = n0 - 128; kmax = 2048; }
    else if (n0 < 384) { W = Wqm; bsrc = bqm; g0 = n0 - 256; kmax = 3072; }
    else               { W = Wqv; bsrc = bqv; g0 = n0 - 384; kmax = 3072; }
    const int tid = threadIdx.x;
    if (kq == 0 && tid < 8) bias[n0 + tid] = bsrc[g0 + tid];

    __shared__ float lt[8][260];
    const int go = tid & 7;
    const int kk = tid >> 3;
    const int nn = tid >> 5;
    const int kc = (tid & 31) * 8;

    for (int i = 0; i < 3; ++i) {
        int kbase = kq * 768 + i * 256;
        __syncthreads();
        #pragma unroll
        for (int kk2 = 0; kk2 < 8; ++kk2) {
            int k = kbase + kk2 * 32 + kk;
            float v = (k < kmax) ? W[(size_t)k * G_ + g0 + go] : 0.0f;
            lt[go][kk2 * 32 + kk] = v;
        }
        __syncthreads();
        uint32_t u0 = pk4fp8(lt[nn][kc + 0] * WSCALE, lt[nn][kc + 1] * WSCALE,
                             lt[nn][kc + 2] * WSCALE, lt[nn][kc + 3] * WSCALE);
        uint32_t u1 = pk4fp8(lt[nn][kc + 4] * WSCALE, lt[nn][kc + 5] * WSCALE,
                             lt[nn][kc + 6] * WSCALE, lt[nn][kc + 7] * WSCALE);
        *(u32x2*)&wt[(size_t)(n0 + nn) * K_TOT + kbase + kc] = (u32x2){u0, u1};
    }
}

// ---------------- GEMM + fused KL (LDS bounce, no global readback) -----------
// Final champion (R29, 81.6 us total).
// R24 champion K-loop. Column remap: local col lc -> gcol =
// (lc>>5)*128 + nbg*32 + (lc&31): block owns g in [nbg*32, nbg*32+32)
// across ALL 4 output segments -> the KL quadruple for each owned (m,g)
// is in the block's registers. Epilogue (2 chunks of 64 rows): waves
// write v = acc*WINV+bias to global AND to klbuf[64][132]; lgkm+barrier;
// each thread reads 4 quadruples from klbuf and accumulates the KL sum.
// No store-drain, no global readback. partial[bid] per block.
__global__ __launch_bounds__(512, 2) void gemm_kernel(
    const float* __restrict__ events, const float* __restrict__ contexts,
    const u8* __restrict__ wt, const float* __restrict__ bias,
    float* __restrict__ out, float* __restrict__ partial)
{
    __shared__ u8 Ab[2][128 * 64];    // fp8 A tiles, swizzled (8 KB each)
    __shared__ u8 Bs[2][128 * 64];    // fp8 B tiles, swizzled (8 KB each)
    __shared__ float klbuf[64 * 132]; // KL bounce buffer (33.8 KB)
    __shared__ float pw[8];

    const int tid = threadIdx.x;
    const int bid = blockIdx.x;
    // 4 nbg-blocks of an A panel share bid&7 -> same XCD.
    const int xx  = bid & 7;
    const int jj  = bid >> 3;            // 0..63
    const int nbg = jj & 3;              // g-group 0..3 (32 g's per group)
    const int mp  = (jj >> 2) * 8 + xx;  // 0..127
    const int m0  = mp * 128;

    const int lane = tid & 63;
    const int w    = tid >> 6;           // 0..7
    const int wm   = (w >> 2) * 64;      // 0 or 64
    const int wn   = (w & 3) * 32;       // 0,32,64,96
    const int lr   = lane & 15;
    const int kg   = lane >> 4;          // k-octet 0..3

    // ---- A staging: row r = tid>>2 (0..127), quarter q = tid&3 ----
    const int r = tid >> 2;
    const int q = tid & 3;
    int m = m0 + r; if (m > M_TOT - 1) m = M_TOT - 1;
    int bb = m / 1023;
    int tt = m - bb * 1023;
    const float* paE = events   + ((size_t)(bb * L_ + tt)) * H_;
    const float* paC = contexts + ((size_t)(bb * (L_ - 1) + tt)) * H_;
    // swizzled ds_write_b32 byte offsets
    int aw[4];
    #pragma unroll
    for (int j = 0; j < 4; ++j)
        aw[j] = r * 64 + (((j ^ ((r >> 1) & 3))) << 4) + q * 4;

    // ---- B staging: 1 gload16/thread, source-preswizzled (16B granule) ----
    // local row bv (0..127) -> wt row (bv>>5)*128 + nbg*32 + (bv&31)
    const int bv   = tid >> 2;
    const int bc   = tid & 3;
    const int bcs  = bc ^ ((bv >> 1) & 3);
    const int bwr  = (bv >> 5) * 128 + nbg * 32 + (bv & 31);
    const u8* bS = wt + (size_t)bwr * K_TOT + bcs * 16;

    // ---- fragment read offsets (bytes; element k = ks*32 + kg*8) ----
    int aoff[4][2], boff[2][2];
    #pragma unroll
    for (int i = 0; i < 4; ++i) {
        int row = wm + i * 16 + lr;
        #pragma unroll
        for (int ks = 0; ks < 2; ++ks) {
            int c16 = ks * 2 + (kg >> 1);
            aoff[i][ks] = row * 64 + ((c16 ^ ((row >> 1) & 3)) << 4) + (kg & 1) * 8;
        }
    }
    #pragma unroll
    for (int j = 0; j < 2; ++j) {
        int nn = wn + j * 16 + lr;
        #pragma unroll
        for (int ks = 0; ks < 2; ++ks) {
            int c16 = ks * 2 + (kg >> 1);
            boff[j][ks] = nn * 64 + ((c16 ^ ((nn >> 1) & 3)) << 4) + (kg & 1) * 8;
        }
    }

    f32x4 acc[4][2];
    #pragma unroll
    for (int i = 0; i < 4; ++i)
        #pragma unroll
        for (int j = 0; j < 2; ++j)
            acc[i][j] = (f32x4){0.f, 0.f, 0.f, 0.f};

    auto stageB = [&](int buf, int kt) {
        gload16(bS + kt * 64, &Bs[buf][tid * 16]);
    };
    auto compute = [&](int buf) {
        #pragma unroll
        for (int ks = 0; ks < 2; ++ks) {
            long a[4], bf[2];
            #pragma unroll
            for (int i = 0; i < 4; ++i)
                a[i] = *(const long*)&Ab[buf][aoff[i][ks]];
            #pragma unroll
            for (int j = 0; j < 2; ++j)
                bf[j] = *(const long*)&Bs[buf][boff[j][ks]];
            __builtin_amdgcn_s_setprio(1);
            #pragma unroll
            for (int i = 0; i < 4; ++i)
                #pragma unroll
                for (int j = 0; j < 2; ++j)
                    acc[i][j] = __builtin_amdgcn_mfma_f32_16x16x32_fp8_fp8(
                        a[i], bf[j], acc[i][j], 0, 0, 0);
            __builtin_amdgcn_s_setprio(0);
        }
    };

    // Named A-staging register sets (2-phase-deep; no arrays -> no scratch)
    f32x4 P0, P1, P2, P3;
    f32x4 Q0, Q1, Q2, Q3;

#define LOADA(p, KT)                                                           \
    {                                                                          \
        int k0_ = (KT) * 64;                                                   \
        int rg_ = (KT) >> 4;                                                   \
        int kq_ = (k0_ & 1023) + q * 4;                                        \
        const float* s_ = (rg_ == 0) ? paE : (rg_ == 1 ? (paE + H_) : paC);    \
        s_ += kq_;                                                             \
        p##0 = *(const f32x4*)(s_ +  0);                                       \
        p##1 = *(const f32x4*)(s_ + 16);                                       \
        p##2 = *(const f32x4*)(s_ + 32);                                       \
        p##3 = *(const f32x4*)(s_ + 48);                                       \
    }
#define CVT1(p, J, BUF)                                                        \
    {                                                                          \
        uint32_t w_ = pk4fp8(p##J[0], p##J[1], p##J[2], p##J[3]);              \
        *(uint32_t*)&Ab[BUF][aw[J]] = w_;                                      \
    }
#define CVTW(p, BUF)  CVT1(p, 0, BUF) CVT1(p, 1, BUF) CVT1(p, 2, BUF) CVT1(p, 3, BUF)

#define WAITV(N)                                                               \
    asm volatile("s_waitcnt vmcnt(" #N ")" ::: "memory");                      \
    __builtin_amdgcn_sched_barrier(0);
#define LGKM0                                                                  \
    asm volatile("s_waitcnt lgkmcnt(0)" ::: "memory");                         \
    __builtin_amdgcn_sched_barrier(0);
#define BAR __builtin_amdgcn_s_barrier()

    // prologue: A(0)->regs->Ab[0]; B(0) in flight; A(1)->Q (in flight)
    LOADA(P, 0);
    stageB(0, 0);
    WAITV(1);            // drain P = A(0) regs, leave B(0)
    CVTW(P, 0);
    LOADA(Q, 1);         // outstanding: B(0) 1 + Q 4 = 5
    LGKM0;               // prologue ds_writes done before first barrier

    for (int t = 0; t < 46; t += 2) {
        // phase t (buf0): consume Q=A(t+1) after WAITV
        LOADA(P, t + 2);
        stageB(1, t + 1);
        WAITV(5); BAR;                 // drains B(t) + Q regs
        compute(0);
        CVTW(Q, 1);
        LGKM0; BAR;
        // phase t+1 (buf1)
        LOADA(Q, t + 3);
        stageB(0, t + 2);
        WAITV(5); BAR;                 // drains B(t+1) + P regs
        compute(1);
        CVTW(P, 0);
        LGKM0; BAR;
    }
    // phase 46 (buf0): Q holds A(47); no more A loads
    stageB(1, 47);
    WAITV(1); BAR;                     // drains B(46) + Q regs, leaves B(47)
    compute(0);
    CVTW(Q, 1);
    LGKM0; BAR;
    // phase 47 (buf1)
    WAITV(0); BAR;
    compute(1);

    // ---- epilogue + fused KL via LDS bounce --------------------------------
    // chunk c covers local rows [32c, 32c+32) of each wm-half:
    //   writer i in {2c, 2c+1}; klbuf lrow = (wm>>1) + (i&1)*16 + kg*4 + rr
    // reader: lrow = tid>>3 (0..63), g-quad gq = (tid&7)*4;
    //   mo = m0 + (lrow&32 ? 64 : 0) + 32c + (lrow&31)
    float s = 0.f;
    #pragma unroll
    for (int c = 0; c < 2; ++c) {
        #pragma unroll
        for (int di = 0; di < 2; ++di) {
            int i = 2 * c + di;
            int mloc = wm + i * 16 + kg * 4;
            int lrb  = (wm >> 1) + di * 16 + kg * 4;
            #pragma unroll
            for (int j = 0; j < 2; ++j) {
                int lcol = wn + j * 16 + lr;
                int seg  = lcol >> 5;
                int gc   = nbg * 32 + (lcol & 31);
                float bv2 = bias[seg * 128 + gc];
                float* ob = out + (size_t)seg * OUT_SEG + gc;
                #pragma unroll
                for (int rr = 0; rr < 4; ++rr) {
                    int mo = m0 + mloc + rr;
                    float v = acc[i][j][rr] * WINV + bv2;
                    if (mo < M_TOT) ob[(size_t)mo * G_] = v;
                    klbuf[(lrb + rr) * 132 + lcol] = v;
                }
            }
        }
        LGKM0; BAR;                    // klbuf chunk visible block-wide
        {
            int lrow = tid >> 3;
            int gq   = (tid & 7) * 4;
            int mo2  = m0 + ((lrow & 32) ? 64 : 0) + 32 * c + (lrow & 31);
            if (mo2 < M_TOT) {
                const float* kb = klbuf + lrow * 132 + gq;
                f32x4 av = *(const f32x4*)(kb +  0);   // zm
                f32x4 bv = *(const f32x4*)(kb + 32);   // zlv
                f32x4 cv = *(const f32x4*)(kb + 64);   // qm
                f32x4 dv = *(const f32x4*)(kb + 96);   // qlv
                #pragma unroll
                for (int e = 0; e < 4; ++e) {
                    float diff = av[e] - cv[e];
                    s += dv[e] - bv[e]
                       + (__expf(bv[e]) + diff * diff) * __expf(-dv[e]) - 1.0f;
                }
            }
        }
        LGKM0; BAR;                    // reads done before next chunk rewrite
    }
    #pragma unroll
    for (int off = 32; off > 0; off >>= 1)
        s += __shfl_down(s, off);
    if (lane == 0) pw[w] = s;
    LGKM0; BAR;
    if (tid == 0) {
        float t2 = 0.f;
        #pragma unroll
        for (int i = 0; i < 8; ++i) t2 += pw[i];
        partial[bid] = t2;
    }

#undef LOADA
#undef CVT1
#undef CVTW
#undef WAITV
#undef LGKM0
#undef BAR
}

// ---------------- KL final: reduce 512 block partials ------------------------
__global__ __launch_bounds__(256) void kl_final(const float* __restrict__ partial,
                                                float* __restrict__ out)
{
    float s = 0.f;
    for (int i = threadIdx.x; i < KL_PARTS; i += 256) s += partial[i];
    #pragma unroll
    for (int off = 32; off > 0; off >>= 1)
        s += __shfl_down(s, off);
    __shared__ float pw[4];
    int wid = threadIdx.x >> 6;
    int lane = threadIdx.x & 63;
    if (lane == 0) pw[wid] = s;
    __syncthreads();
    if (threadIdx.x == 0)
        out[KL_IDX] = 0.5f * (pw[0] + pw[1] + pw[2] + pw[3]) / (float)M_TOT;
}

// ---------------- launcher ----------------------------------------------------
extern "C" void kernel_launch(void* const* d_in, const int* in_sizes, int n_in,
                              void* d_out, int out_size, void* d_ws, size_t ws_size,
                              hipStream_t stream)
{
    const float* events   = (const float*)d_in[0];
    const float* contexts = (const float*)d_in[1];
    const float* Wzm = (const float*)d_in[2];
    const float* bzm = (const float*)d_in[3];
    const float* Wzv = (const float*)d_in[4];
    const float* bzv = (const float*)d_in[5];
    const float* Wqm = (const float*)d_in[6];
    const float* bqm = (const float*)d_in[7];
    const float* Wqv = (const float*)d_in[8];
    const float* bqv = (const float*)d_in[9];
    float* out = (float*)d_out;

    u8*    wt      = (u8*)((char*)d_ws + WS_WT_OFF);
    float* bias    = (float*)((char*)d_ws + WS_BIAS_OFF);
    float* partial = (float*)((char*)d_ws + WS_PART_OFF);

    prep_kernel<<<256, 256, 0, stream>>>(Wzm, bzm, Wzv, bzv, Wqm, bqm, Wqv, bqv,
                                         wt, bias);
    gemm_kernel<<<512, 512, 0, stream>>>(events, contexts, wt, bias, out, partial);
    kl_final<<<1, 256, 0, stream>>>(partial, out);
}

// Round 31
// 81.413 us; speedup vs baseline: 1.4147x; 1.0012x over previous
//
#include <hip/hip_runtime.h>
#include <stdint.h>

typedef unsigned char u8;
typedef unsigned short u16;
typedef __attribute__((ext_vector_type(4))) float f32x4;
typedef __attribute__((ext_vector_type(2))) uint32_t u32x2;

#define B_      16
#define L_      1024
#define H_      1024
#define G_      128
#define M_TOT   16368            // B*(L-1)
#define K_TOT   3072
#define OUT_SEG 2095104          // M_TOT*G_
#define KL_IDX  (4*OUT_SEG)
#define KL_PARTS 512             // one partial per gemm block
#define WSCALE  128.0f
#define WINV    0.0078125f       // 1/128

// ws layout
#define WS_WT_OFF    0           // fp8 W'T [512][3072] = 1,572,864 B
#define WS_BIAS_OFF  1572864     // float[512]
#define WS_PART_OFF  1574912     // float[512] block partials

__device__ inline void gload16(const void* g, void* l) {
    __builtin_amdgcn_global_load_lds(
        (const __attribute__((address_space(1))) void*)g,
        (__attribute__((address_space(3))) void*)l, 16, 0, 0);
}

// pack 4 floats -> 4 fp8 (e4m3, OCP on gfx950) in one u32, k-ascending bytes
__device__ inline uint32_t pk4fp8(float f0, float f1, float f2, float f3) {
    uint32_t w = __builtin_amdgcn_cvt_pk_fp8_f32(f0, f1, 0, 0);
    w = __builtin_amdgcn_cvt_pk_fp8_f32(f2, f3, w, 1);
    return w;
}

// ---------------- prep: build W'T fp8 (x128) [512][3072] + bias[512] ---------
__global__ __launch_bounds__(256) void prep_kernel(
    const float* __restrict__ Wzm, const float* __restrict__ bzm,
    const float* __restrict__ Wzv, const float* __restrict__ bzv,
    const float* __restrict__ Wqm, const float* __restrict__ bqm,
    const float* __restrict__ Wqv, const float* __restrict__ bqv,
    u8* __restrict__ wt, float* __restrict__ bias)
{
    const int ng = blockIdx.x >> 2;
    const int kq = blockIdx.x & 3;
    const int n0 = ng * 8;
    const float* W; const float* bsrc; int g0; int kmax;
    if (n0 < 128)      { W = Wzm; bsrc = bzm; g0 = n0;       kmax = 2048; }
    else if (n0 < 256) { W = Wzv; bsrc = bzv; g0 = n0 - 128; kmax = 2048; }
    else if (n0 < 384) { W = Wqm; bsrc = bqm; g0 = n0 - 256; kmax = 3072; }
    else               { W = Wqv; bsrc = bqv; g0 = n0 - 384; kmax = 3072; }
    const int tid = threadIdx.x;
    if (kq == 0 && tid < 8) bias[n0 + tid] = bsrc[g0 + tid];

    __shared__ float lt[8][260];
    const int go = tid & 7;
    const int kk = tid >> 3;
    const int nn = tid >> 5;
    const int kc = (tid & 31) * 8;

    for (int i = 0; i < 3; ++i) {
        int kbase = kq * 768 + i * 256;
        __syncthreads();
        #pragma unroll
        for (int kk2 = 0; kk2 < 8; ++kk2) {
            int k = kbase + kk2 * 32 + kk;
            float v = (k < kmax) ? W[(size_t)k * G_ + g0 + go] : 0.0f;
            lt[go][kk2 * 32 + kk] = v;
        }
        __syncthreads();
        uint32_t u0 = pk4fp8(lt[nn][kc + 0] * WSCALE, lt[nn][kc + 1] * WSCALE,
                             lt[nn][kc + 2] * WSCALE, lt[nn][kc + 3] * WSCALE);
        uint32_t u1 = pk4fp8(lt[nn][kc + 4] * WSCALE, lt[nn][kc + 5] * WSCALE,
                             lt[nn][kc + 6] * WSCALE, lt[nn][kc + 7] * WSCALE);
        *(u32x2*)&wt[(size_t)(n0 + nn) * K_TOT + kbase + kc] = (u32x2){u0, u1};
    }
}

// ---------------- GEMM + fused KL (LDS bounce, no global readback) -----------
// Final champion (R29/R30, 81.5 us total).
// R24 champion K-loop. Column remap: local col lc -> gcol =
// (lc>>5)*128 + nbg*32 + (lc&31): block owns g in [nbg*32, nbg*32+32)
// across ALL 4 output segments -> the KL quadruple for each owned (m,g)
// is in the block's registers. Epilogue (2 chunks of 64 rows): waves
// write v = acc*WINV+bias to global AND to klbuf[64][132]; lgkm+barrier;
// each thread reads 4 quadruples from klbuf and accumulates the KL sum.
// No store-drain, no global readback. partial[bid] per block.
__global__ __launch_bounds__(512, 2) void gemm_kernel(
    const float* __restrict__ events, const float* __restrict__ contexts,
    const u8* __restrict__ wt, const float* __restrict__ bias,
    float* __restrict__ out, float* __restrict__ partial)
{
    __shared__ u8 Ab[2][128 * 64];    // fp8 A tiles, swizzled (8 KB each)
    __shared__ u8 Bs[2][128 * 64];    // fp8 B tiles, swizzled (8 KB each)
    __shared__ float klbuf[64 * 132]; // KL bounce buffer (33.8 KB)
    __shared__ float pw[8];

    const int tid = threadIdx.x;
    const int bid = blockIdx.x;
    // 4 nbg-blocks of an A panel share bid&7 -> same XCD.
    const int xx  = bid & 7;
    const int jj  = bid >> 3;            // 0..63
    const int nbg = jj & 3;              // g-group 0..3 (32 g's per group)
    const int mp  = (jj >> 2) * 8 + xx;  // 0..127
    const int m0  = mp * 128;

    const int lane = tid & 63;
    const int w    = tid >> 6;           // 0..7
    const int wm   = (w >> 2) * 64;      // 0 or 64
    const int wn   = (w & 3) * 32;       // 0,32,64,96
    const int lr   = lane & 15;
    const int kg   = lane >> 4;          // k-octet 0..3

    // ---- A staging: row r = tid>>2 (0..127), quarter q = tid&3 ----
    const int r = tid >> 2;
    const int q = tid & 3;
    int m = m0 + r; if (m > M_TOT - 1) m = M_TOT - 1;
    int bb = m / 1023;
    int tt = m - bb * 1023;
    const float* paE = events   + ((size_t)(bb * L_ + tt)) * H_;
    const float* paC = contexts + ((size_t)(bb * (L_ - 1) + tt)) * H_;
    // swizzled ds_write_b32 byte offsets
    int aw[4];
    #pragma unroll
    for (int j = 0; j < 4; ++j)
        aw[j] = r * 64 + (((j ^ ((r >> 1) & 3))) << 4) + q * 4;

    // ---- B staging: 1 gload16/thread, source-preswizzled (16B granule) ----
    // local row bv (0..127) -> wt row (bv>>5)*128 + nbg*32 + (bv&31)
    const int bv   = tid >> 2;
    const int bc   = tid & 3;
    const int bcs  = bc ^ ((bv >> 1) & 3);
    const int bwr  = (bv >> 5) * 128 + nbg * 32 + (bv & 31);
    const u8* bS = wt + (size_t)bwr * K_TOT + bcs * 16;

    // ---- fragment read offsets (bytes; element k = ks*32 + kg*8) ----
    int aoff[4][2], boff[2][2];
    #pragma unroll
    for (int i = 0; i < 4; ++i) {
        int row = wm + i * 16 + lr;
        #pragma unroll
        for (int ks = 0; ks < 2; ++ks) {
            int c16 = ks * 2 + (kg >> 1);
            aoff[i][ks] = row * 64 + ((c16 ^ ((row >> 1) & 3)) << 4) + (kg & 1) * 8;
        }
    }
    #pragma unroll
    for (int j = 0; j < 2; ++j) {
        int nn = wn + j * 16 + lr;
        #pragma unroll
        for (int ks = 0; ks < 2; ++ks) {
            int c16 = ks * 2 + (kg >> 1);
            boff[j][ks] = nn * 64 + ((c16 ^ ((nn >> 1) & 3)) << 4) + (kg & 1) * 8;
        }
    }

    f32x4 acc[4][2];
    #pragma unroll
    for (int i = 0; i < 4; ++i)
        #pragma unroll
        for (int j = 0; j < 2; ++j)
            acc[i][j] = (f32x4){0.f, 0.f, 0.f, 0.f};

    auto stageB = [&](int buf, int kt) {
        gload16(bS + kt * 64, &Bs[buf][tid * 16]);
    };
    auto compute = [&](int buf) {
        #pragma unroll
        for (int ks = 0; ks < 2; ++ks) {
            long a[4], bf[2];
            #pragma unroll
            for (int i = 0; i < 4; ++i)
                a[i] = *(const long*)&Ab[buf][aoff[i][ks]];
            #pragma unroll
            for (int j = 0; j < 2; ++j)
                bf[j] = *(const long*)&Bs[buf][boff[j][ks]];
            __builtin_amdgcn_s_setprio(1);
            #pragma unroll
            for (int i = 0; i < 4; ++i)
                #pragma unroll
                for (int j = 0; j < 2; ++j)
                    acc[i][j] = __builtin_amdgcn_mfma_f32_16x16x32_fp8_fp8(
                        a[i], bf[j], acc[i][j], 0, 0, 0);
            __builtin_amdgcn_s_setprio(0);
        }
    };

    // Named A-staging register sets (2-phase-deep; no arrays -> no scratch)
    f32x4 P0, P1, P2, P3;
    f32x4 Q0, Q1, Q2, Q3;

#define LOADA(p, KT)                                                           \
    {                                                                          \
        int k0_ = (KT) * 64;                                                   \
        int rg_ = (KT) >> 4;                                                   \
        int kq_ = (k0_ & 1023) + q * 4;                                        \
        const float* s_ = (rg_ == 0) ? paE : (rg_ == 1 ? (paE + H_) : paC);    \
        s_ += kq_;                                                             \
        p##0 = *(const f32x4*)(s_ +  0);                                       \
        p##1 = *(const f32x4*)(s_ + 16);                                       \
        p##2 = *(const f32x4*)(s_ + 32);                                       \
        p##3 = *(const f32x4*)(s_ + 48);                                       \
    }
#define CVT1(p, J, BUF)                                                        \
    {                                                                          \
        uint32_t w_ = pk4fp8(p##J[0], p##J[1], p##J[2], p##J[3]);              \
        *(uint32_t*)&Ab[BUF][aw[J]] = w_;                                      \
    }
#define CVTW(p, BUF)  CVT1(p, 0, BUF) CVT1(p, 1, BUF) CVT1(p, 2, BUF) CVT1(p, 3, BUF)

#define WAITV(N)                                                               \
    asm volatile("s_waitcnt vmcnt(" #N ")" ::: "memory");                      \
    __builtin_amdgcn_sched_barrier(0);
#define LGKM0                                                                  \
    asm volatile("s_waitcnt lgkmcnt(0)" ::: "memory");                         \
    __builtin_amdgcn_sched_barrier(0);
#define BAR __builtin_amdgcn_s_barrier()

    // prologue: A(0)->regs->Ab[0]; B(0) in flight; A(1)->Q (in flight)
    LOADA(P, 0);
    stageB(0, 0);
    WAITV(1);            // drain P = A(0) regs, leave B(0)
    CVTW(P, 0);
    LOADA(Q, 1);         // outstanding: B(0) 1 + Q 4 = 5
    LGKM0;               // prologue ds_writes done before first barrier

    for (int t = 0; t < 46; t += 2) {
        // phase t (buf0): consume Q=A(t+1) after WAITV
        LOADA(P, t + 2);
        stageB(1, t + 1);
        WAITV(5); BAR;                 // drains B(t) + Q regs
        compute(0);
        CVTW(Q, 1);
        LGKM0; BAR;
        // phase t+1 (buf1)
        LOADA(Q, t + 3);
        stageB(0, t + 2);
        WAITV(5); BAR;                 // drains B(t+1) + P regs
        compute(1);
        CVTW(P, 0);
        LGKM0; BAR;
    }
    // phase 46 (buf0): Q holds A(47); no more A loads
    stageB(1, 47);
    WAITV(1); BAR;                     // drains B(46) + Q regs, leaves B(47)
    compute(0);
    CVTW(Q, 1);
    LGKM0; BAR;
    // phase 47 (buf1)
    WAITV(0); BAR;
    compute(1);

    // ---- epilogue + fused KL via LDS bounce --------------------------------
    // chunk c covers local rows [32c, 32c+32) of each wm-half:
    //   writer i in {2c, 2c+1}; klbuf lrow = (wm>>1) + (i&1)*16 + kg*4 + rr
    // reader: lrow = tid>>3 (0..63), g-quad gq = (tid&7)*4;
    //   mo = m0 + (lrow&32 ? 64 : 0) + 32c + (lrow&31)
    float s = 0.f;
    #pragma unroll
    for (int c = 0; c < 2; ++c) {
        #pragma unroll
        for (int di = 0; di < 2; ++di) {
            int i = 2 * c + di;
            int mloc = wm + i * 16 + kg * 4;
            int lrb  = (wm >> 1) + di * 16 + kg * 4;
            #pragma unroll
            for (int j = 0; j < 2; ++j) {
                int lcol = wn + j * 16 + lr;
                int seg  = lcol >> 5;
                int gc   = nbg * 32 + (lcol & 31);
                float bv2 = bias[seg * 128 + gc];
                float* ob = out + (size_t)seg * OUT_SEG + gc;
                #pragma unroll
                for (int rr = 0; rr < 4; ++rr) {
                    int mo = m0 + mloc + rr;
                    float v = acc[i][j][rr] * WINV + bv2;
                    if (mo < M_TOT) ob[(size_t)mo * G_] = v;
                    klbuf[(lrb + rr) * 132 + lcol] = v;
                }
            }
        }
        LGKM0; BAR;                    // klbuf chunk visible block-wide
        {
            int lrow = tid >> 3;
            int gq   = (tid & 7) * 4;
            int mo2  = m0 + ((lrow & 32) ? 64 : 0) + 32 * c + (lrow & 31);
            if (mo2 < M_TOT) {
                const float* kb = klbuf + lrow * 132 + gq;
                f32x4 av = *(const f32x4*)(kb +  0);   // zm
                f32x4 bv = *(const f32x4*)(kb + 32);   // zlv
                f32x4 cv = *(const f32x4*)(kb + 64);   // qm
                f32x4 dv = *(const f32x4*)(kb + 96);   // qlv
                #pragma unroll
                for (int e = 0; e < 4; ++e) {
                    float diff = av[e] - cv[e];
                    s += dv[e] - bv[e]
                       + (__expf(bv[e]) + diff * diff) * __expf(-dv[e]) - 1.0f;
                }
            }
        }
        LGKM0; BAR;                    // reads done before next chunk rewrite
    }
    #pragma unroll
    for (int off = 32; off > 0; off >>= 1)
        s += __shfl_down(s, off);
    if (lane == 0) pw[w] = s;
    LGKM0; BAR;
    if (tid == 0) {
        float t2 = 0.f;
        #pragma unroll
        for (int i = 0; i < 8; ++i) t2 += pw[i];
        partial[bid] = t2;
    }

#undef LOADA
#undef CVT1
#undef CVTW
#undef WAITV
#undef LGKM0
#undef BAR
}

// ---------------- KL final: reduce 512 block partials ------------------------
__global__ __launch_bounds__(256) void kl_final(const float* __restrict__ partial,
                                                float* __restrict__ out)
{
    float s = 0.f;
    for (int i = threadIdx.x; i < KL_PARTS; i += 256) s += partial[i];
    #pragma unroll
    for (int off = 32; off > 0; off >>= 1)
        s += __shfl_down(s, off);
    __shared__ float pw[4];
    int wid = threadIdx.x >> 6;
    int lane = threadIdx.x & 63;
    if (lane == 0) pw[wid] = s;
    __syncthreads();
    if (threadIdx.x == 0)
        out[KL_IDX] = 0.5f * (pw[0] + pw[1] + pw[2] + pw[3]) / (float)M_TOT;
}

// ---------------- launcher ----------------------------------------------------
extern "C" void kernel_launch(void* const* d_in, const int* in_sizes, int n_in,
                              void* d_out, int out_size, void* d_ws, size_t ws_size,
                              hipStream_t stream)
{
    const float* events   = (const float*)d_in[0];
    const float* contexts = (const float*)d_in[1];
    const float* Wzm = (const float*)d_in[2];
    const float* bzm = (const float*)d_in[3];
    const float* Wzv = (const float*)d_in[4];
    const float* bzv = (const float*)d_in[5];
    const float* Wqm = (const float*)d_in[6];
    const float* bqm = (const float*)d_in[7];
    const float* Wqv = (const float*)d_in[8];
    const float* bqv = (const float*)d_in[9];
    float* out = (float*)d_out;

    u8*    wt      = (u8*)((char*)d_ws + WS_WT_OFF);
    float* bias    = (float*)((char*)d_ws + WS_BIAS_OFF);
    float* partial = (float*)((char*)d_ws + WS_PART_OFF);

    prep_kernel<<<256, 256, 0, stream>>>(Wzm, bzm, Wzv, bzv, Wqm, bqm, Wqv, bqv,
                                         wt, bias);
    gemm_kernel<<<512, 512, 0, stream>>>(events, contexts, wt, bias, out, partial);
    kl_final<<<1, 256, 0, stream>>>(partial, out);
}